// Round 3
// 1274.565 us; speedup vs baseline: 1.0249x; 1.0249x over previous
//
#include <hip/hip_runtime.h>
#include <hip/hip_bf16.h>
#include <math.h>

// ---------------- problem constants ----------------
constexpr int B_ = 2, T_ = 1024, D_ = 768, H_ = 12, L_ = 4, V_ = 32000;
constexpr int M_ = B_ * T_;          // 2048 token rows
constexpr int FF_ = 4 * D_;          // 3072
constexpr int QKVN_ = 3 * D_;        // 2304
#define EMB_SCALE 27.712812921102035f
#define EPS_ 1e-5f

typedef __attribute__((ext_vector_type(8))) short short8_t;
typedef __attribute__((ext_vector_type(4))) float float4_t;

__device__ __forceinline__ float bf2f(__hip_bfloat16 v) { return __bfloat162float(v); }
__device__ __forceinline__ __hip_bfloat16 f2bf(float v) { return __float2bfloat16(v); }

// async global->LDS, 16B per lane; lds dest is wave-uniform base + lane*16
__device__ __forceinline__ void gl_lds16(const __hip_bfloat16* g, __hip_bfloat16* l) {
    __builtin_amdgcn_global_load_lds(
        (const __attribute__((address_space(1))) void*)g,
        (__attribute__((address_space(3))) void*)l, 16, 0, 0);
}

// ---------------- weight convert (plain f32 -> bf16) ----------------
__global__ __launch_bounds__(256) void convert_kernel(
    const float* __restrict__ src, __hip_bfloat16* __restrict__ dst, size_t n)
{
    size_t i = ((size_t)blockIdx.x * 256 + threadIdx.x) * 4;
    if (i + 3 < n) {
        float4 f = *(const float4*)(src + i);
        dst[i + 0] = f2bf(f.x);
        dst[i + 1] = f2bf(f.y);
        dst[i + 2] = f2bf(f.z);
        dst[i + 3] = f2bf(f.w);
    }
}

// ------------- transpose + convert: src f32 [K,N] -> dst bf16 [N,K] -------------
__global__ __launch_bounds__(256) void tconv_kernel(
    const float* __restrict__ src, __hip_bfloat16* __restrict__ dst,
    int K, int N, size_t sstride, size_t dstride)
{
    __shared__ float tile[32][33];
    const float* S = src + (size_t)blockIdx.z * sstride;
    __hip_bfloat16* Dd = dst + (size_t)blockIdx.z * dstride;
    int n0 = blockIdx.x * 32, k0 = blockIdx.y * 32;
    int tx = threadIdx.x & 31, ty = threadIdx.x >> 5; // 32 x 8
#pragma unroll
    for (int i = 0; i < 32; i += 8)
        tile[ty + i][tx] = S[(size_t)(k0 + ty + i) * N + n0 + tx];
    __syncthreads();
#pragma unroll
    for (int i = 0; i < 32; i += 8)
        Dd[(size_t)(n0 + ty + i) * K + k0 + tx] = f2bf(tile[tx][ty + i]);
}

// ---------------- embedding ----------------
__global__ __launch_bounds__(256) void embed_kernel(
    const int* __restrict__ idx, const float* __restrict__ wte,
    const float* __restrict__ wpe, float* __restrict__ x)
{
    int row = blockIdx.x, tid = threadIdx.x;
    int t = row & (T_ - 1);
    int tok = idx[row];
#pragma unroll
    for (int i = 0; i < 3; ++i) {
        int c = i * 256 + tid;
        x[(size_t)row * D_ + c] =
            (wte[(size_t)tok * D_ + c] + wpe[(size_t)t * D_ + c]) * EMB_SCALE;
    }
}

// ---------------- DynamicTanh ----------------
__global__ __launch_bounds__(256) void dyt_kernel(
    const float* __restrict__ x, __hip_bfloat16* __restrict__ h,
    const float* __restrict__ w, const float* __restrict__ bb,
    const float* __restrict__ alpha_p)
{
    const int row = blockIdx.x, tid = threadIdx.x;
    const float* xr = x + (size_t)row * D_;
    float v[3];
    float s = 0.f, ss = 0.f;
#pragma unroll
    for (int i = 0; i < 3; ++i) {
        v[i] = xr[i * 256 + tid];
        s += v[i];
        ss += v[i] * v[i];
    }
#pragma unroll
    for (int off = 32; off >= 1; off >>= 1) {
        s  += __shfl_xor(s,  off, 64);
        ss += __shfl_xor(ss, off, 64);
    }
    __shared__ float sh[8];
    int wave = tid >> 6;
    if ((tid & 63) == 0) { sh[wave] = s; sh[wave + 4] = ss; }
    __syncthreads();
    s  = sh[0] + sh[1] + sh[2] + sh[3];
    ss = sh[4] + sh[5] + sh[6] + sh[7];
    float mu = s * (1.f / D_);
    float var = ss * (1.f / D_) - mu * mu;
    float rstd = rsqrtf(var + EPS_);
    float alpha = *alpha_p;
#pragma unroll
    for (int i = 0; i < 3; ++i) {
        int c = i * 256 + tid;
        float xn = (v[i] - mu) * rstd;
        h[(size_t)row * D_ + c] = f2bf(w[c] * tanhf(alpha * xn) + bb[c]);
    }
}

// ---------------- flash attention: 256 thr, 4 waves, Q-tile 64 rows ----------------
// qkv rows [M, 2304]: q at +0, k at +768, v at +1536. o rows [M, 768].
constexpr int LSTR = 72;   // LDS row stride (elements); 144 B, 16B-aligned rows

__global__ __launch_bounds__(256) void fattn_kernel(
    const __hip_bfloat16* __restrict__ qkv, __hip_bfloat16* __restrict__ o)
{
    const int qt = gridDim.x - 1 - blockIdx.x;   // longest blocks first
    const int hh = blockIdx.y, b = blockIdx.z;
    const int q0 = qt * 64;
    const int tid = threadIdx.x;
    const int wave = tid >> 6, lane = tid & 63;
    const int quad = lane >> 4, l16 = lane & 15;
    const size_t rs = QKVN_;

    __shared__ __hip_bfloat16 Ks[64 * LSTR];      // [k][d]
    __shared__ __hip_bfloat16 Vts[64 * LSTR];     // [d][k] (transposed)
    __shared__ __hip_bfloat16 Ps[4][16 * LSTR];   // per-wave P strip [m][k]

    // Q A-frags: rows q0 + wave*16 + l16, d chunks quad*8 (+32)
    const __hip_bfloat16* qrow = qkv + (size_t)(b * T_ + q0 + wave * 16 + l16) * rs + hh * 64;
    short8_t qf0 = *(const short8_t*)(qrow + quad * 8);
    short8_t qf1 = *(const short8_t*)(qrow + 32 + quad * 8);

    float4_t Oacc[4];
#pragma unroll
    for (int j = 0; j < 4; ++j) Oacc[j] = (float4_t){0.f, 0.f, 0.f, 0.f};
    float mrow[4], lrow[4];
#pragma unroll
    for (int r = 0; r < 4; ++r) { mrow[r] = -1e30f; lrow[r] = 0.f; }

    const __hip_bfloat16* kbase = qkv + (size_t)b * T_ * rs + D_ + hh * 64;
    const __hip_bfloat16* vbase = qkv + (size_t)b * T_ * rs + 2 * D_ + hh * 64;

    const int sr = tid >> 2;            // K staging: row 0..63
    const int sc = (tid & 3) * 8;       // K staging: d chunk
    const int vr = lane;                // V staging: row (k)
    const int vc0 = wave * 16;          // V staging: d chunk start

    for (int kt = 0; kt <= qt; ++kt) {
        const int kt0 = kt * 64;
        uint4 kv0 = *(const uint4*)(kbase + (size_t)(kt0 + sr) * rs + sc);
        uint4 kv1 = *(const uint4*)(kbase + (size_t)(kt0 + sr) * rs + sc + 32);
        uint4 vv0 = *(const uint4*)(vbase + (size_t)(kt0 + vr) * rs + vc0);
        uint4 vv1 = *(const uint4*)(vbase + (size_t)(kt0 + vr) * rs + vc0 + 8);
        __syncthreads();   // WAR: prev tile's frag reads done
        *(uint4*)(Ks + sr * LSTR + sc)      = kv0;
        *(uint4*)(Ks + sr * LSTR + sc + 32) = kv1;
        {
            const __hip_bfloat16* vp = (const __hip_bfloat16*)&vv0;
#pragma unroll
            for (int i = 0; i < 8; ++i) Vts[(vc0 + i) * LSTR + vr] = vp[i];
            vp = (const __hip_bfloat16*)&vv1;
#pragma unroll
            for (int i = 0; i < 8; ++i) Vts[(vc0 + 8 + i) * LSTR + vr] = vp[i];
        }
        __syncthreads();

        // ---- S strip = Q(16) x K^T(64) ----
        float4_t S[4];
#pragma unroll
        for (int jt = 0; jt < 4; ++jt) {
            short8_t kf0 = *(const short8_t*)(Ks + (jt * 16 + l16) * LSTR + quad * 8);
            short8_t kf1 = *(const short8_t*)(Ks + (jt * 16 + l16) * LSTR + 32 + quad * 8);
            float4_t s = (float4_t){0.f, 0.f, 0.f, 0.f};
            s = __builtin_amdgcn_mfma_f32_16x16x32_bf16(qf0, kf0, s, 0, 0, 0);
            s = __builtin_amdgcn_mfma_f32_16x16x32_bf16(qf1, kf1, s, 0, 0, 0);
            S[jt] = s;
        }

        // ---- scale + causal mask (diag tile only) ----
        if (kt == qt) {
#pragma unroll
            for (int jt = 0; jt < 4; ++jt)
#pragma unroll
                for (int r = 0; r < 4; ++r) {
                    int qg = wave * 16 + quad * 4 + r;
                    int kg = jt * 16 + l16;
                    S[jt][r] = (kg > qg) ? -1e30f : S[jt][r] * 0.125f;
                }
        } else {
#pragma unroll
            for (int jt = 0; jt < 4; ++jt)
#pragma unroll
                for (int r = 0; r < 4; ++r) S[jt][r] *= 0.125f;
        }

        // ---- online softmax (rows = quad*4+r, reduce across 16-lane group) ----
        float mnew[4], alphav[4];
#pragma unroll
        for (int r = 0; r < 4; ++r) {
            float mx = fmaxf(fmaxf(S[0][r], S[1][r]), fmaxf(S[2][r], S[3][r]));
            mx = fmaxf(mx, __shfl_xor(mx, 1, 64));
            mx = fmaxf(mx, __shfl_xor(mx, 2, 64));
            mx = fmaxf(mx, __shfl_xor(mx, 4, 64));
            mx = fmaxf(mx, __shfl_xor(mx, 8, 64));
            mnew[r] = fmaxf(mrow[r], mx);
            alphav[r] = __expf(mrow[r] - mnew[r]);
            mrow[r] = mnew[r];
        }
        float psum[4] = {0.f, 0.f, 0.f, 0.f};
#pragma unroll
        for (int jt = 0; jt < 4; ++jt)
#pragma unroll
            for (int r = 0; r < 4; ++r) {
                float p = __expf(S[jt][r] - mnew[r]);
                S[jt][r] = p;
                psum[r] += p;
            }
#pragma unroll
        for (int r = 0; r < 4; ++r) {
            float ps = psum[r];
            ps += __shfl_xor(ps, 1, 64);
            ps += __shfl_xor(ps, 2, 64);
            ps += __shfl_xor(ps, 4, 64);
            ps += __shfl_xor(ps, 8, 64);
            lrow[r] = lrow[r] * alphav[r] + ps;
        }

        // ---- P strip: C-layout regs -> LDS [m][k] (own wave only, no barrier) ----
        __hip_bfloat16* ps_base = Ps[wave];
#pragma unroll
        for (int jt = 0; jt < 4; ++jt)
#pragma unroll
            for (int r = 0; r < 4; ++r)
                ps_base[(quad * 4 + r) * LSTR + jt * 16 + l16] = f2bf(S[jt][r]);

        // ---- rescale O, then O += P @ V ----
#pragma unroll
        for (int j = 0; j < 4; ++j)
#pragma unroll
            for (int r = 0; r < 4; ++r) Oacc[j][r] *= alphav[r];

        short8_t pf0 = *(const short8_t*)(ps_base + l16 * LSTR + quad * 8);
        short8_t pf1 = *(const short8_t*)(ps_base + l16 * LSTR + 32 + quad * 8);
#pragma unroll
        for (int j = 0; j < 4; ++j) {
            short8_t vf0 = *(const short8_t*)(Vts + (j * 16 + l16) * LSTR + quad * 8);
            short8_t vf1 = *(const short8_t*)(Vts + (j * 16 + l16) * LSTR + 32 + quad * 8);
            Oacc[j] = __builtin_amdgcn_mfma_f32_16x16x32_bf16(pf0, vf0, Oacc[j], 0, 0, 0);
            Oacc[j] = __builtin_amdgcn_mfma_f32_16x16x32_bf16(pf1, vf1, Oacc[j], 0, 0, 0);
        }
    }

    // ---- epilogue: O /= l, write ----
    float inv_l[4];
#pragma unroll
    for (int r = 0; r < 4; ++r) inv_l[r] = 1.f / lrow[r];
    __hip_bfloat16* orow = o + (size_t)(b * T_ + q0 + wave * 16) * D_ + hh * 64;
#pragma unroll
    for (int j = 0; j < 4; ++j)
#pragma unroll
        for (int r = 0; r < 4; ++r)
            orow[(size_t)(quad * 4 + r) * D_ + j * 16 + l16] = f2bf(Oacc[j][r] * inv_l[r]);
}

// ---------------- GEMM: C[M,N] = A[M,K] @ Bt[N,K]^T, bf16 in, f32 acc ----------------
// EPI: 0 = bf16 out (no bias), 1 = f32 out = res + acc + bias,
//      2 = bf16 out = gelu(acc + bias), 3 = f32 out = acc
__device__ __forceinline__ float gelu_exact(float t) {
    return 0.5f * t * (1.0f + erff(t * 0.70710678118654752f));
}

template <int EPI>
__global__ __launch_bounds__(256, 2) void gemm_bt(
    const __hip_bfloat16* __restrict__ A, const __hip_bfloat16* __restrict__ Bt,
    float* __restrict__ outF, __hip_bfloat16* __restrict__ outB,
    const float* __restrict__ bias, const float* __restrict__ res,
    int M, int N, int K)
{
    __shared__ __hip_bfloat16 As[128 * 32];
    __shared__ __hip_bfloat16 Bs[128 * 32];
    const int tid = threadIdx.x;
    const int wave = tid >> 6, lane = tid & 63;
    const int quad = lane >> 4, l16 = lane & 15;
    const int m0 = blockIdx.y * 128, n0 = blockIdx.x * 128;
    const int wm = (wave >> 1) * 64, wn = (wave & 1) * 64;

    float4_t acc[4][4];
#pragma unroll
    for (int i = 0; i < 4; ++i)
#pragma unroll
        for (int j = 0; j < 4; ++j) acc[i][j] = (float4_t){0.f, 0.f, 0.f, 0.f};

    // global_load_lds staging: wave w stages As/Bs rows [w*16, w*16+16) and +64.
    // lane -> (row lr, 16B chunk lc); lds dest = wave-uniform base + lane*16B.
    const int lr = lane >> 2, lc = (lane & 3) * 8;
    const __hip_bfloat16* ga0 = A  + (size_t)(m0 + wave * 16 + lr) * K + lc;
    const __hip_bfloat16* ga1 = A  + (size_t)(m0 + 64 + wave * 16 + lr) * K + lc;
    const __hip_bfloat16* gb0 = Bt + (size_t)(n0 + wave * 16 + lr) * K + lc;
    const __hip_bfloat16* gb1 = Bt + (size_t)(n0 + 64 + wave * 16 + lr) * K + lc;
    __hip_bfloat16* la0 = As + (wave * 16) * 32;
    __hip_bfloat16* la1 = As + (64 + wave * 16) * 32;
    __hip_bfloat16* lb0 = Bs + (wave * 16) * 32;
    __hip_bfloat16* lb1 = Bs + (64 + wave * 16) * 32;

    for (int k0 = 0; k0 < K; k0 += 32) {
        __syncthreads();  // prev iteration's fragment reads complete
        gl_lds16(ga0 + k0, la0);
        gl_lds16(ga1 + k0, la1);
        gl_lds16(gb0 + k0, lb0);
        gl_lds16(gb1 + k0, lb1);
        __syncthreads();  // drains vmcnt(0): staged data visible
        short8_t af[4], bfv[4];
#pragma unroll
        for (int i = 0; i < 4; ++i) {
            af[i]  = *(const short8_t*)(As + (wm + i * 16 + l16) * 32 + quad * 8);
            bfv[i] = *(const short8_t*)(Bs + (wn + i * 16 + l16) * 32 + quad * 8);
        }
#pragma unroll
        for (int i = 0; i < 4; ++i)
#pragma unroll
            for (int j = 0; j < 4; ++j)
                acc[i][j] = __builtin_amdgcn_mfma_f32_16x16x32_bf16(
                    af[i], bfv[j], acc[i][j], 0, 0, 0);
    }

#pragma unroll
    for (int i = 0; i < 4; ++i) {
#pragma unroll
        for (int j = 0; j < 4; ++j) {
            int colg = n0 + wn + j * 16 + l16;
#pragma unroll
            for (int rg = 0; rg < 4; ++rg) {
                int rowg = m0 + wm + i * 16 + quad * 4 + rg;
                size_t offo = (size_t)rowg * N + colg;
                float v = acc[i][j][rg];
                if (EPI == 0) {
                    outB[offo] = f2bf(v);
                } else if (EPI == 1) {
                    outF[offo] = res[offo] + v + bias[colg];
                } else if (EPI == 2) {
                    outB[offo] = f2bf(gelu_exact(v + bias[colg]));
                } else {
                    outF[offo] = v;
                }
            }
        }
    }
}

// ---------------- lm_head GEMM: 256x256 tile, 8 waves, phase-pipelined ----------------
// C[2048, 32000] f32 = A[2048,768] @ Bt[32000,768]^T.
// Schedule: per 32-wide K-tile, 2 phases (row-half regions). Each phase:
//   {ds_read frags | issue 1 half-region prefetch via global_load_lds}
//   -> s_barrier -> lgkmcnt(0)+sched_barrier -> setprio(1) 16xMFMA setprio(0) -> s_barrier.
// vmcnt(2) ONLY at tile boundaries (2 loads stay in flight across every barrier).
// TAIL FIX: tile NT-2 ends with vmcnt(0) — tile NT-1's half-1 loads have no younger
// issues behind them, so vmcnt(2) there would leave them in flight while P1 reads
// half-1 B-fragments (the round-2 correctness failure).
// LDS 64 KiB: [parity][A|B][row-half][512 granules of 16B], granule slot
// s = 4*lr + (q ^ ((lr>>1)&3))  (XOR swizzle -> conflict-free ds_read_b128),
// realized by pre-swizzling the *global* source address (linear gl_lds dest).
__global__ __launch_bounds__(512, 2) void gemm_lmhead(
    const __hip_bfloat16* __restrict__ A, const __hip_bfloat16* __restrict__ Bt,
    float* __restrict__ out)
{
    constexpr int K = D_;        // 768
    constexpr int N = V_;        // 32000
    constexpr int NT = K / 32;   // 24 K-tiles
    __shared__ __hip_bfloat16 lds[32768];   // 64 KiB

    const int tid  = threadIdx.x;
    const int wave = tid >> 6, lane = tid & 63;
    const int quad = lane >> 4, l16 = lane & 15;

    // XCD-chunked, m-fast tile order: XCD x owns tiles g in [x*125, x*125+125);
    // g = n_idx*8 + m_idx (m fast) -> 8 consecutive blocks share one B-panel in L2,
    // and all of A (3 MB) is L2-resident.
    const int flat = blockIdx.x;                 // 0..999
    const int g = (flat & 7) * 125 + (flat >> 3);
    const int m0 = (g & 7) * 256, n0 = (g >> 3) * 256;

    const int wm = (wave >> 2) * 128;            // 2 waves in M
    const int wn = (wave & 3) * 64;              // 4 waves in N

    // ---- stage source mapping (inverse of LDS swizzle) ----
    const int slr  = tid >> 2;                               // local row 0..127
    const int sq   = (tid & 3) ^ ((slr >> 1) & 3);           // k-granule 0..3
    const int rbase = ((slr & 64) << 1) | (slr & 63);        // global row bits 0-5,7
    const __hip_bfloat16* gA = A  + (size_t)(m0 + rbase) * K + sq * 8;
    const __hip_bfloat16* gB = Bt + (size_t)(n0 + rbase) * K + sq * 8;
    const int wb = wave * 1024;   // this wave's 1 KiB chunk within a region
    char* ldsc = (char*)lds;

    // stage one 8 KiB half-region; X: 0 = A, 16384 = B; hh = row-half; tt = K-tile
#define STG(gp, Xoff, hh, tt) \
    gl_lds16((gp) + (size_t)(hh) * 64 * K + (tt) * 32, \
             (__hip_bfloat16*)(ldsc + (((tt) & 1) * 32768 + (Xoff) + (hh) * 8192 + wb)))

    // ds_read per-lane byte offsets within a parity buffer
    const int xe   = (quad ^ ((l16 >> 1) & 3)) * 16;
    const int aoff = wm * 32 + l16 * 64 + xe;
    const int boff = 16384 + ((wn >> 6) & 1) * 8192 + (wn & 128) * 32 + l16 * 64 + xe;

    float4_t acc[8][4];
#pragma unroll
    for (int i = 0; i < 8; ++i)
#pragma unroll
        for (int j = 0; j < 4; ++j) acc[i][j] = (float4_t){0.f, 0.f, 0.f, 0.f};

    // ---- prologue: tile 0 fully + tile 1 half0; keep 2 loads outstanding ----
    STG(gA, 0,     0, 0); STG(gB, 16384, 0, 0);
    STG(gA, 0,     1, 0); STG(gB, 16384, 1, 0);
    STG(gA, 0,     0, 1); STG(gB, 16384, 0, 1);
    asm volatile("s_waitcnt vmcnt(2)" ::: "memory");
    __builtin_amdgcn_sched_barrier(0);
    __builtin_amdgcn_s_barrier();

    auto do_tile = [&](int tt, bool last2) {
        const char* base = ldsc + (tt & 1) * 32768;
        short8_t af[4], bf[4];
        // ---- phase 1 (row-half 0): read frags, prefetch (tt+1, half 1) ----
#pragma unroll
        for (int ii = 0; ii < 4; ++ii)
            af[ii] = *(const short8_t*)(base + ii * 1024 + aoff);
#pragma unroll
        for (int j = 0; j < 4; ++j)
            bf[j] = *(const short8_t*)(base + j * 1024 + boff);
        if (tt + 1 < NT) { STG(gA, 0, 1, tt + 1); STG(gB, 16384, 1, tt + 1); }
        __builtin_amdgcn_s_barrier();
        asm volatile("s_waitcnt lgkmcnt(0)" ::: "memory");
        __builtin_amdgcn_sched_barrier(0);
        __builtin_amdgcn_s_setprio(1);
#pragma unroll
        for (int ii = 0; ii < 4; ++ii)
#pragma unroll
            for (int j = 0; j < 4; ++j)
                acc[ii][j] = __builtin_amdgcn_mfma_f32_16x16x32_bf16(
                    af[ii], bf[j], acc[ii][j], 0, 0, 0);
        __builtin_amdgcn_s_setprio(0);
        __builtin_amdgcn_s_barrier();
        // ---- phase 2 (row-half 1): read A frags (B reused), prefetch (tt+2, half 0) ----
#pragma unroll
        for (int ii = 0; ii < 4; ++ii)
            af[ii] = *(const short8_t*)(base + 8192 + ii * 1024 + aoff);
        if (tt + 2 < NT) { STG(gA, 0, 0, tt + 2); STG(gB, 16384, 0, tt + 2); }
        __builtin_amdgcn_s_barrier();
        asm volatile("s_waitcnt lgkmcnt(0)" ::: "memory");
        __builtin_amdgcn_sched_barrier(0);
        __builtin_amdgcn_s_setprio(1);
#pragma unroll
        for (int ii = 0; ii < 4; ++ii)
#pragma unroll
            for (int j = 0; j < 4; ++j)
                acc[4 + ii][j] = __builtin_amdgcn_mfma_f32_16x16x32_bf16(
                    af[ii], bf[j], acc[4 + ii][j], 0, 0, 0);
        __builtin_amdgcn_s_setprio(0);
        if (last2) {
            // tail: tile NT-1's half-1 loads are the newest in the queue ->
            // counted wait can't cover them; full drain once, just before last tile.
            asm volatile("s_waitcnt vmcnt(0)" ::: "memory");
        } else {
            asm volatile("s_waitcnt vmcnt(2)" ::: "memory");   // counted, never 0
        }
        __builtin_amdgcn_sched_barrier(0);
        __builtin_amdgcn_s_barrier();
    };

    for (int t = 0; t + 2 < NT; t += 2) { do_tile(t, false); do_tile(t + 1, false); }
    do_tile(NT - 2, true);
    do_tile(NT - 1, false);
#undef STG

    // ---- epilogue: f32 store ----
    float* orow = out + (size_t)(m0 + wm + quad * 4) * N + (n0 + wn + l16);
#pragma unroll
    for (int i = 0; i < 8; ++i)
#pragma unroll
        for (int j = 0; j < 4; ++j)
#pragma unroll
            for (int rg = 0; rg < 4; ++rg)
                orow[(size_t)(i * 16 + rg) * N + j * 16] = acc[i][j][rg];
}

// ---------------- launch ----------------
extern "C" void kernel_launch(void* const* d_in, const int* in_sizes, int n_in,
                              void* d_out, int out_size, void* d_ws, size_t ws_size,
                              hipStream_t stream)
{
    const int*   idx   = (const int*)d_in[0];
    const float* wte   = (const float*)d_in[1];
    const float* wpe   = (const float*)d_in[2];
    const float* ln1_a = (const float*)d_in[3];
    const float* ln1_w = (const float*)d_in[4];
    const float* ln1_b = (const float*)d_in[5];
    const float* wq    = (const float*)d_in[6];
    const float* wk    = (const float*)d_in[7];
    const float* wv    = (const float*)d_in[8];
    const float* wo    = (const float*)d_in[9];
    const float* bo    = (const float*)d_in[10];
    const float* ln2_a = (const float*)d_in[11];
    const float* ln2_w = (const float*)d_in[12];
    const float* ln2_b = (const float*)d_in[13];
    const float* w_fc  = (const float*)d_in[14];
    const float* b_fc  = (const float*)d_in[15];
    const float* w_pr  = (const float*)d_in[16];
    const float* b_pr  = (const float*)d_in[17];
    const float* lnf_a = (const float*)d_in[18];
    const float* lnf_w = (const float*)d_in[19];
    const float* lnf_b = (const float*)d_in[20];
    float* out = (float*)d_out;

    char* ws = (char*)d_ws;
    size_t off = 0;
    auto alloc = [&](size_t bytes) -> char* {
        char* p = ws + off;
        off += (bytes + 255) & ~(size_t)255;
        return p;
    };
    __hip_bfloat16* wqkv_t = (__hip_bfloat16*)alloc((size_t)L_ * QKVN_ * D_ * 2);
    __hip_bfloat16* wo_t   = (__hip_bfloat16*)alloc((size_t)L_ * D_ * D_ * 2);
    __hip_bfloat16* wfc_t  = (__hip_bfloat16*)alloc((size_t)L_ * FF_ * D_ * 2);
    __hip_bfloat16* wpr_t  = (__hip_bfloat16*)alloc((size_t)L_ * D_ * FF_ * 2);
    __hip_bfloat16* wte_b  = (__hip_bfloat16*)alloc((size_t)V_ * D_ * 2);
    float*          x      = (float*)alloc((size_t)M_ * D_ * 4);
    __hip_bfloat16* h      = (__hip_bfloat16*)alloc((size_t)M_ * D_ * 2);
    __hip_bfloat16* qkv    = (__hip_bfloat16*)alloc((size_t)M_ * QKVN_ * 2);
    __hip_bfloat16* attno  = (__hip_bfloat16*)alloc((size_t)M_ * D_ * 2);
    __hip_bfloat16* mid    = (__hip_bfloat16*)alloc((size_t)M_ * FF_ * 2);
    (void)ws_size; (void)in_sizes; (void)n_in; (void)out_size;

    // ---- weight prep (bf16, [N,K] layout) ----
    {
        size_t n = (size_t)V_ * D_;
        convert_kernel<<<dim3((unsigned)(n / 1024)), 256, 0, stream>>>(wte, wte_b, n);
    }
    size_t wstride = (size_t)D_ * D_;
    tconv_kernel<<<dim3(24, 24, L_), 256, 0, stream>>>(wq, wqkv_t + 0,            D_, D_, wstride, (size_t)QKVN_ * D_);
    tconv_kernel<<<dim3(24, 24, L_), 256, 0, stream>>>(wk, wqkv_t + (size_t)D_ * D_,   D_, D_, wstride, (size_t)QKVN_ * D_);
    tconv_kernel<<<dim3(24, 24, L_), 256, 0, stream>>>(wv, wqkv_t + (size_t)2 * D_ * D_, D_, D_, wstride, (size_t)QKVN_ * D_);
    tconv_kernel<<<dim3(24, 24, L_), 256, 0, stream>>>(wo, wo_t,                  D_, D_, wstride, wstride);
    tconv_kernel<<<dim3(96, 24, L_), 256, 0, stream>>>(w_fc, wfc_t, D_, FF_, (size_t)D_ * FF_, (size_t)FF_ * D_);
    tconv_kernel<<<dim3(24, 96, L_), 256, 0, stream>>>(w_pr, wpr_t, FF_, D_, (size_t)FF_ * D_, (size_t)D_ * FF_);

    // ---- embedding ----
    embed_kernel<<<dim3(M_), 256, 0, stream>>>(idx, wte, wpe, x);

    // ---- transformer layers ----
    for (int l = 0; l < L_; ++l) {
        dyt_kernel<<<dim3(M_), 256, 0, stream>>>(x, h, ln1_w + l * D_, ln1_b + l * D_, ln1_a + l);
        gemm_bt<0><<<dim3(QKVN_ / 128, M_ / 128), 256, 0, stream>>>(
            h, wqkv_t + (size_t)l * QKVN_ * D_, nullptr, qkv, nullptr, nullptr, M_, QKVN_, D_);
        fattn_kernel<<<dim3(T_ / 64, H_, B_), 256, 0, stream>>>(qkv, attno);
        gemm_bt<1><<<dim3(D_ / 128, M_ / 128), 256, 0, stream>>>(
            attno, wo_t + (size_t)l * D_ * D_, x, nullptr, bo + l * D_, x, M_, D_, D_);
        dyt_kernel<<<dim3(M_), 256, 0, stream>>>(x, h, ln2_w + l * D_, ln2_b + l * D_, ln2_a + l);
        gemm_bt<2><<<dim3(FF_ / 128, M_ / 128), 256, 0, stream>>>(
            h, wfc_t + (size_t)l * FF_ * D_, nullptr, mid, b_fc + l * FF_, nullptr, M_, FF_, D_);
        gemm_bt<1><<<dim3(D_ / 128, M_ / 128), 256, 0, stream>>>(
            mid, wpr_t + (size_t)l * D_ * FF_, x, nullptr, b_pr + l * D_, x, M_, D_, FF_);
    }

    // ---- final DyT + lm_head (256x256 phase-pipelined) ----
    dyt_kernel<<<dim3(M_), 256, 0, stream>>>(x, h, lnf_w, lnf_b, lnf_a);
    gemm_lmhead<<<dim3((M_ / 256) * (V_ / 256)), 512, 0, stream>>>(h, wte_b, out);
}

// Round 4
// 1125.882 us; speedup vs baseline: 1.1602x; 1.1321x over previous
//
#include <hip/hip_runtime.h>
#include <hip/hip_bf16.h>
#include <math.h>

// ---------------- problem constants ----------------
constexpr int B_ = 2, T_ = 1024, D_ = 768, H_ = 12, L_ = 4, V_ = 32000;
constexpr int M_ = B_ * T_;          // 2048 token rows
constexpr int FF_ = 4 * D_;          // 3072
constexpr int QKVN_ = 3 * D_;        // 2304
#define EMB_SCALE 27.712812921102035f
#define EPS_ 1e-5f

typedef __attribute__((ext_vector_type(8))) short short8_t;
typedef __attribute__((ext_vector_type(4))) float float4_t;

__device__ __forceinline__ float bf2f(__hip_bfloat16 v) { return __bfloat162float(v); }
__device__ __forceinline__ __hip_bfloat16 f2bf(float v) { return __float2bfloat16(v); }

// async global->LDS, 16B per lane; lds dest is wave-uniform base + lane*16
__device__ __forceinline__ void gl_lds16(const __hip_bfloat16* g, __hip_bfloat16* l) {
    __builtin_amdgcn_global_load_lds(
        (const __attribute__((address_space(1))) void*)g,
        (__attribute__((address_space(3))) void*)l, 16, 0, 0);
}

// ---------------- weight convert (plain f32 -> bf16) ----------------
__global__ __launch_bounds__(256) void convert_kernel(
    const float* __restrict__ src, __hip_bfloat16* __restrict__ dst, size_t n)
{
    size_t i = ((size_t)blockIdx.x * 256 + threadIdx.x) * 4;
    if (i + 3 < n) {
        float4 f = *(const float4*)(src + i);
        dst[i + 0] = f2bf(f.x);
        dst[i + 1] = f2bf(f.y);
        dst[i + 2] = f2bf(f.z);
        dst[i + 3] = f2bf(f.w);
    }
}

// ------------- transpose + convert: src f32 [K,N] -> dst bf16 [N,K] -------------
__global__ __launch_bounds__(256) void tconv_kernel(
    const float* __restrict__ src, __hip_bfloat16* __restrict__ dst,
    int K, int N, size_t sstride, size_t dstride)
{
    __shared__ float tile[32][33];
    const float* S = src + (size_t)blockIdx.z * sstride;
    __hip_bfloat16* Dd = dst + (size_t)blockIdx.z * dstride;
    int n0 = blockIdx.x * 32, k0 = blockIdx.y * 32;
    int tx = threadIdx.x & 31, ty = threadIdx.x >> 5; // 32 x 8
#pragma unroll
    for (int i = 0; i < 32; i += 8)
        tile[ty + i][tx] = S[(size_t)(k0 + ty + i) * N + n0 + tx];
    __syncthreads();
#pragma unroll
    for (int i = 0; i < 32; i += 8)
        Dd[(size_t)(n0 + ty + i) * K + k0 + tx] = f2bf(tile[tx][ty + i]);
}

// ---------------- embedding ----------------
__global__ __launch_bounds__(256) void embed_kernel(
    const int* __restrict__ idx, const float* __restrict__ wte,
    const float* __restrict__ wpe, float* __restrict__ x)
{
    int row = blockIdx.x, tid = threadIdx.x;
    int t = row & (T_ - 1);
    int tok = idx[row];
#pragma unroll
    for (int i = 0; i < 3; ++i) {
        int c = i * 256 + tid;
        x[(size_t)row * D_ + c] =
            (wte[(size_t)tok * D_ + c] + wpe[(size_t)t * D_ + c]) * EMB_SCALE;
    }
}

// ---------------- DynamicTanh ----------------
__global__ __launch_bounds__(256) void dyt_kernel(
    const float* __restrict__ x, __hip_bfloat16* __restrict__ h,
    const float* __restrict__ w, const float* __restrict__ bb,
    const float* __restrict__ alpha_p)
{
    const int row = blockIdx.x, tid = threadIdx.x;
    const float* xr = x + (size_t)row * D_;
    float v[3];
    float s = 0.f, ss = 0.f;
#pragma unroll
    for (int i = 0; i < 3; ++i) {
        v[i] = xr[i * 256 + tid];
        s += v[i];
        ss += v[i] * v[i];
    }
#pragma unroll
    for (int off = 32; off >= 1; off >>= 1) {
        s  += __shfl_xor(s,  off, 64);
        ss += __shfl_xor(ss, off, 64);
    }
    __shared__ float sh[8];
    int wave = tid >> 6;
    if ((tid & 63) == 0) { sh[wave] = s; sh[wave + 4] = ss; }
    __syncthreads();
    s  = sh[0] + sh[1] + sh[2] + sh[3];
    ss = sh[4] + sh[5] + sh[6] + sh[7];
    float mu = s * (1.f / D_);
    float var = ss * (1.f / D_) - mu * mu;
    float rstd = rsqrtf(var + EPS_);
    float alpha = *alpha_p;
#pragma unroll
    for (int i = 0; i < 3; ++i) {
        int c = i * 256 + tid;
        float xn = (v[i] - mu) * rstd;
        h[(size_t)row * D_ + c] = f2bf(w[c] * tanhf(alpha * xn) + bb[c]);
    }
}

// ---------------- flash attention: 256 thr, 4 waves, Q-tile 64 rows ----------------
// qkv rows [M, 2304]: q at +0, k at +768, v at +1536. o rows [M, 768].
constexpr int LSTR = 72;   // LDS row stride (elements); 144 B, 16B-aligned rows

__global__ __launch_bounds__(256) void fattn_kernel(
    const __hip_bfloat16* __restrict__ qkv, __hip_bfloat16* __restrict__ o)
{
    const int qt = gridDim.x - 1 - blockIdx.x;   // longest blocks first
    const int hh = blockIdx.y, b = blockIdx.z;
    const int q0 = qt * 64;
    const int tid = threadIdx.x;
    const int wave = tid >> 6, lane = tid & 63;
    const int quad = lane >> 4, l16 = lane & 15;
    const size_t rs = QKVN_;

    __shared__ __hip_bfloat16 Ks[64 * LSTR];      // [k][d]
    __shared__ __hip_bfloat16 Vts[64 * LSTR];     // [d][k] (transposed)
    __shared__ __hip_bfloat16 Ps[4][16 * LSTR];   // per-wave P strip [m][k]

    // Q A-frags: rows q0 + wave*16 + l16, d chunks quad*8 (+32)
    const __hip_bfloat16* qrow = qkv + (size_t)(b * T_ + q0 + wave * 16 + l16) * rs + hh * 64;
    short8_t qf0 = *(const short8_t*)(qrow + quad * 8);
    short8_t qf1 = *(const short8_t*)(qrow + 32 + quad * 8);

    float4_t Oacc[4];
#pragma unroll
    for (int j = 0; j < 4; ++j) Oacc[j] = (float4_t){0.f, 0.f, 0.f, 0.f};
    float mrow[4], lrow[4];
#pragma unroll
    for (int r = 0; r < 4; ++r) { mrow[r] = -1e30f; lrow[r] = 0.f; }

    const __hip_bfloat16* kbase = qkv + (size_t)b * T_ * rs + D_ + hh * 64;
    const __hip_bfloat16* vbase = qkv + (size_t)b * T_ * rs + 2 * D_ + hh * 64;

    const int sr = tid >> 2;            // K staging: row 0..63
    const int sc = (tid & 3) * 8;       // K staging: d chunk
    const int vr = lane;                // V staging: row (k)
    const int vc0 = wave * 16;          // V staging: d chunk start

    for (int kt = 0; kt <= qt; ++kt) {
        const int kt0 = kt * 64;
        uint4 kv0 = *(const uint4*)(kbase + (size_t)(kt0 + sr) * rs + sc);
        uint4 kv1 = *(const uint4*)(kbase + (size_t)(kt0 + sr) * rs + sc + 32);
        uint4 vv0 = *(const uint4*)(vbase + (size_t)(kt0 + vr) * rs + vc0);
        uint4 vv1 = *(const uint4*)(vbase + (size_t)(kt0 + vr) * rs + vc0 + 8);
        __syncthreads();   // WAR: prev tile's frag reads done
        *(uint4*)(Ks + sr * LSTR + sc)      = kv0;
        *(uint4*)(Ks + sr * LSTR + sc + 32) = kv1;
        {
            const __hip_bfloat16* vp = (const __hip_bfloat16*)&vv0;
#pragma unroll
            for (int i = 0; i < 8; ++i) Vts[(vc0 + i) * LSTR + vr] = vp[i];
            vp = (const __hip_bfloat16*)&vv1;
#pragma unroll
            for (int i = 0; i < 8; ++i) Vts[(vc0 + 8 + i) * LSTR + vr] = vp[i];
        }
        __syncthreads();

        // ---- S strip = Q(16) x K^T(64) ----
        float4_t S[4];
#pragma unroll
        for (int jt = 0; jt < 4; ++jt) {
            short8_t kf0 = *(const short8_t*)(Ks + (jt * 16 + l16) * LSTR + quad * 8);
            short8_t kf1 = *(const short8_t*)(Ks + (jt * 16 + l16) * LSTR + 32 + quad * 8);
            float4_t s = (float4_t){0.f, 0.f, 0.f, 0.f};
            s = __builtin_amdgcn_mfma_f32_16x16x32_bf16(qf0, kf0, s, 0, 0, 0);
            s = __builtin_amdgcn_mfma_f32_16x16x32_bf16(qf1, kf1, s, 0, 0, 0);
            S[jt] = s;
        }

        // ---- scale + causal mask (diag tile only) ----
        if (kt == qt) {
#pragma unroll
            for (int jt = 0; jt < 4; ++jt)
#pragma unroll
                for (int r = 0; r < 4; ++r) {
                    int qg = wave * 16 + quad * 4 + r;
                    int kg = jt * 16 + l16;
                    S[jt][r] = (kg > qg) ? -1e30f : S[jt][r] * 0.125f;
                }
        } else {
#pragma unroll
            for (int jt = 0; jt < 4; ++jt)
#pragma unroll
                for (int r = 0; r < 4; ++r) S[jt][r] *= 0.125f;
        }

        // ---- online softmax (rows = quad*4+r, reduce across 16-lane group) ----
        float mnew[4], alphav[4];
#pragma unroll
        for (int r = 0; r < 4; ++r) {
            float mx = fmaxf(fmaxf(S[0][r], S[1][r]), fmaxf(S[2][r], S[3][r]));
            mx = fmaxf(mx, __shfl_xor(mx, 1, 64));
            mx = fmaxf(mx, __shfl_xor(mx, 2, 64));
            mx = fmaxf(mx, __shfl_xor(mx, 4, 64));
            mx = fmaxf(mx, __shfl_xor(mx, 8, 64));
            mnew[r] = fmaxf(mrow[r], mx);
            alphav[r] = __expf(mrow[r] - mnew[r]);
            mrow[r] = mnew[r];
        }
        float psum[4] = {0.f, 0.f, 0.f, 0.f};
#pragma unroll
        for (int jt = 0; jt < 4; ++jt)
#pragma unroll
            for (int r = 0; r < 4; ++r) {
                float p = __expf(S[jt][r] - mnew[r]);
                S[jt][r] = p;
                psum[r] += p;
            }
#pragma unroll
        for (int r = 0; r < 4; ++r) {
            float ps = psum[r];
            ps += __shfl_xor(ps, 1, 64);
            ps += __shfl_xor(ps, 2, 64);
            ps += __shfl_xor(ps, 4, 64);
            ps += __shfl_xor(ps, 8, 64);
            lrow[r] = lrow[r] * alphav[r] + ps;
        }

        // ---- P strip: C-layout regs -> LDS [m][k] (own wave only, no barrier) ----
        __hip_bfloat16* ps_base = Ps[wave];
#pragma unroll
        for (int jt = 0; jt < 4; ++jt)
#pragma unroll
            for (int r = 0; r < 4; ++r)
                ps_base[(quad * 4 + r) * LSTR + jt * 16 + l16] = f2bf(S[jt][r]);

        // ---- rescale O, then O += P @ V ----
#pragma unroll
        for (int j = 0; j < 4; ++j)
#pragma unroll
            for (int r = 0; r < 4; ++r) Oacc[j][r] *= alphav[r];

        short8_t pf0 = *(const short8_t*)(ps_base + l16 * LSTR + quad * 8);
        short8_t pf1 = *(const short8_t*)(ps_base + l16 * LSTR + 32 + quad * 8);
#pragma unroll
        for (int j = 0; j < 4; ++j) {
            short8_t vf0 = *(const short8_t*)(Vts + (j * 16 + l16) * LSTR + quad * 8);
            short8_t vf1 = *(const short8_t*)(Vts + (j * 16 + l16) * LSTR + 32 + quad * 8);
            Oacc[j] = __builtin_amdgcn_mfma_f32_16x16x32_bf16(pf0, vf0, Oacc[j], 0, 0, 0);
            Oacc[j] = __builtin_amdgcn_mfma_f32_16x16x32_bf16(pf1, vf1, Oacc[j], 0, 0, 0);
        }
    }

    // ---- epilogue: O /= l, write ----
    float inv_l[4];
#pragma unroll
    for (int r = 0; r < 4; ++r) inv_l[r] = 1.f / lrow[r];
    __hip_bfloat16* orow = o + (size_t)(b * T_ + q0 + wave * 16) * D_ + hh * 64;
#pragma unroll
    for (int j = 0; j < 4; ++j)
#pragma unroll
        for (int r = 0; r < 4; ++r)
            orow[(size_t)(quad * 4 + r) * D_ + j * 16 + l16] = f2bf(Oacc[j][r] * inv_l[r]);
}

// ---------------- pipelined GEMM: C[M,N] = A[M,K] @ Bt[N,K]^T, 128x128 tile ----------------
// Ring-4 LDS buffers (4 x 16KB), prefetch distance 3, ONE barrier + counted vmcnt per
// K-step (lm_head-verified ledger). Granule XOR-swizzle (src-preswizzled, swizzled
// ds_read) kills bank conflicts. EPI: 0 = bf16 out, 1 = f32 out = res + acc + bias,
// 2 = bf16 out = gelu(acc + bias), 3 = f32 out = acc.
// vmcnt ledger: prologue issues tiles 0,1,2 (12 loads), waits vmcnt(8) -> tile 0 done.
// Iter t: issue tile t+3 (if any); read frags of tile t; MFMA; end-wait ensures tile
// t+1 done: vmcnt(8) while t+3<NT, vmcnt(4) at t==NT-3, vmcnt(0) at t==NT-2, none at NT-1.
__device__ __forceinline__ float gelu_exact(float t) {
    return 0.5f * t * (1.0f + erff(t * 0.70710678118654752f));
}

template <int EPI>
__global__ __launch_bounds__(256, 2) void gemm_btp(
    const __hip_bfloat16* __restrict__ A, const __hip_bfloat16* __restrict__ Bt,
    float* __restrict__ outF, __hip_bfloat16* __restrict__ outB,
    const float* __restrict__ bias, const float* __restrict__ res,
    int M, int N, int K)
{
    __shared__ __hip_bfloat16 lds[4 * 8192];   // 4 ring buffers x (A 8KB + B 8KB)
    const int tid = threadIdx.x;
    const int wave = tid >> 6, lane = tid & 63;
    const int quad = lane >> 4, l16 = lane & 15;
    const int m0 = blockIdx.y * 128, n0 = blockIdx.x * 128;
    const int wm = (wave >> 1) * 64, wn = (wave & 1) * 64;
    const int NT = K >> 5;   // K-tiles of 32 (all call sites: 24 or 96, >= 3)

    // stage mapping: thread -> (row srow per 64-row chunk, pre-swizzled src k-granule)
    const int srow = tid >> 2;                          // 0..63
    const int sq   = (tid & 3) ^ ((srow >> 1) & 3);     // src granule (inverse swizzle)
    const __hip_bfloat16* gA = A  + (size_t)(m0 + srow) * K + sq * 8;
    const __hip_bfloat16* gB = Bt + (size_t)(n0 + srow) * K + sq * 8;
    char* ldsc = (char*)lds;
    const int wb = wave * 1024;   // this wave's 1KB within each 4KB stage chunk

    // one STGP = 4 gl_lds calls x 4 waves x 1KB = full 16KB tile (A rows 0-63, 64-127; B same)
#define STGP(tt) do {                                                      \
        const size_t ko = (size_t)(tt) * 32;                               \
        char* bb = ldsc + ((tt) & 3) * 16384 + wb;                         \
        gl_lds16(gA + ko,                  (__hip_bfloat16*)(bb));         \
        gl_lds16(gA + (size_t)64 * K + ko, (__hip_bfloat16*)(bb + 4096));  \
        gl_lds16(gB + ko,                  (__hip_bfloat16*)(bb + 8192));  \
        gl_lds16(gB + (size_t)64 * K + ko, (__hip_bfloat16*)(bb + 12288)); \
    } while (0)

    // swizzled ds_read: granule (row, q) lives at phys slot q ^ ((row>>1)&3);
    // row = 16*const + l16 -> phys offset depends only on l16.
    const int xe = (quad ^ ((l16 >> 1) & 3)) * 16;

    float4_t acc[4][4];
#pragma unroll
    for (int i = 0; i < 4; ++i)
#pragma unroll
        for (int j = 0; j < 4; ++j) acc[i][j] = (float4_t){0.f, 0.f, 0.f, 0.f};

    // ---- prologue: tiles 0,1,2 in flight; wait tile 0 (8 left outstanding) ----
    STGP(0); STGP(1); STGP(2);
    asm volatile("s_waitcnt vmcnt(8)" ::: "memory");
    __builtin_amdgcn_sched_barrier(0);
    __builtin_amdgcn_s_barrier();

    for (int t = 0; t < NT; ++t) {
        // entry invariant: tile t staged & visible to all waves; t+1,t+2 in flight.
        if (t + 3 < NT) STGP(t + 3);   // WAR vs buf[(t-1)&3] safe: barrier crossed
        const char* base = ldsc + (t & 3) * 16384;
        short8_t af[4], bfv[4];
#pragma unroll
        for (int i = 0; i < 4; ++i)
            af[i]  = *(const short8_t*)(base + (wm + i * 16 + l16) * 64 + xe);
#pragma unroll
        for (int j = 0; j < 4; ++j)
            bfv[j] = *(const short8_t*)(base + 8192 + (wn + j * 16 + l16) * 64 + xe);
        asm volatile("s_waitcnt lgkmcnt(0)" ::: "memory");
        __builtin_amdgcn_sched_barrier(0);
        __builtin_amdgcn_s_setprio(1);
#pragma unroll
        for (int i = 0; i < 4; ++i)
#pragma unroll
            for (int j = 0; j < 4; ++j)
                acc[i][j] = __builtin_amdgcn_mfma_f32_16x16x32_bf16(
                    af[i], bfv[j], acc[i][j], 0, 0, 0);
        __builtin_amdgcn_s_setprio(0);
        // end-wait: tile t+1's 4 loads complete (counted; drains only at tail)
        if (t + 3 < NT) {
            asm volatile("s_waitcnt vmcnt(8)" ::: "memory");
        } else if (t + 2 < NT) {
            asm volatile("s_waitcnt vmcnt(4)" ::: "memory");
        } else if (t + 1 < NT) {
            asm volatile("s_waitcnt vmcnt(0)" ::: "memory");
        }
        __builtin_amdgcn_sched_barrier(0);
        __builtin_amdgcn_s_barrier();
    }
#undef STGP

#pragma unroll
    for (int i = 0; i < 4; ++i) {
#pragma unroll
        for (int j = 0; j < 4; ++j) {
            int colg = n0 + wn + j * 16 + l16;
#pragma unroll
            for (int rg = 0; rg < 4; ++rg) {
                int rowg = m0 + wm + i * 16 + quad * 4 + rg;
                size_t offo = (size_t)rowg * N + colg;
                float v = acc[i][j][rg];
                if (EPI == 0) {
                    outB[offo] = f2bf(v);
                } else if (EPI == 1) {
                    outF[offo] = res[offo] + v + bias[colg];
                } else if (EPI == 2) {
                    outB[offo] = f2bf(gelu_exact(v + bias[colg]));
                } else {
                    outF[offo] = v;
                }
            }
        }
    }
}

// ---------------- lm_head GEMM: 256x256 tile, 8 waves, phase-pipelined ----------------
// (verified passing in round 3 — unchanged)
__global__ __launch_bounds__(512, 2) void gemm_lmhead(
    const __hip_bfloat16* __restrict__ A, const __hip_bfloat16* __restrict__ Bt,
    float* __restrict__ out)
{
    constexpr int K = D_;        // 768
    constexpr int N = V_;        // 32000
    constexpr int NT = K / 32;   // 24 K-tiles
    __shared__ __hip_bfloat16 lds[32768];   // 64 KiB

    const int tid  = threadIdx.x;
    const int wave = tid >> 6, lane = tid & 63;
    const int quad = lane >> 4, l16 = lane & 15;

    const int flat = blockIdx.x;                 // 0..999
    const int g = (flat & 7) * 125 + (flat >> 3);
    const int m0 = (g & 7) * 256, n0 = (g >> 3) * 256;

    const int wm = (wave >> 2) * 128;            // 2 waves in M
    const int wn = (wave & 3) * 64;              // 4 waves in N

    const int slr  = tid >> 2;                               // local row 0..127
    const int sq   = (tid & 3) ^ ((slr >> 1) & 3);           // k-granule 0..3
    const int rbase = ((slr & 64) << 1) | (slr & 63);        // global row bits 0-5,7
    const __hip_bfloat16* gA = A  + (size_t)(m0 + rbase) * K + sq * 8;
    const __hip_bfloat16* gB = Bt + (size_t)(n0 + rbase) * K + sq * 8;
    const int wb = wave * 1024;   // this wave's 1 KiB chunk within a region
    char* ldsc = (char*)lds;

#define STG(gp, Xoff, hh, tt) \
    gl_lds16((gp) + (size_t)(hh) * 64 * K + (tt) * 32, \
             (__hip_bfloat16*)(ldsc + (((tt) & 1) * 32768 + (Xoff) + (hh) * 8192 + wb)))

    const int xe   = (quad ^ ((l16 >> 1) & 3)) * 16;
    const int aoff = wm * 32 + l16 * 64 + xe;
    const int boff = 16384 + ((wn >> 6) & 1) * 8192 + (wn & 128) * 32 + l16 * 64 + xe;

    float4_t acc[8][4];
#pragma unroll
    for (int i = 0; i < 8; ++i)
#pragma unroll
        for (int j = 0; j < 4; ++j) acc[i][j] = (float4_t){0.f, 0.f, 0.f, 0.f};

    STG(gA, 0,     0, 0); STG(gB, 16384, 0, 0);
    STG(gA, 0,     1, 0); STG(gB, 16384, 1, 0);
    STG(gA, 0,     0, 1); STG(gB, 16384, 0, 1);
    asm volatile("s_waitcnt vmcnt(2)" ::: "memory");
    __builtin_amdgcn_sched_barrier(0);
    __builtin_amdgcn_s_barrier();

    auto do_tile = [&](int tt, bool last2) {
        const char* base = ldsc + (tt & 1) * 32768;
        short8_t af[4], bf[4];
#pragma unroll
        for (int ii = 0; ii < 4; ++ii)
            af[ii] = *(const short8_t*)(base + ii * 1024 + aoff);
#pragma unroll
        for (int j = 0; j < 4; ++j)
            bf[j] = *(const short8_t*)(base + j * 1024 + boff);
        if (tt + 1 < NT) { STG(gA, 0, 1, tt + 1); STG(gB, 16384, 1, tt + 1); }
        __builtin_amdgcn_s_barrier();
        asm volatile("s_waitcnt lgkmcnt(0)" ::: "memory");
        __builtin_amdgcn_sched_barrier(0);
        __builtin_amdgcn_s_setprio(1);
#pragma unroll
        for (int ii = 0; ii < 4; ++ii)
#pragma unroll
            for (int j = 0; j < 4; ++j)
                acc[ii][j] = __builtin_amdgcn_mfma_f32_16x16x32_bf16(
                    af[ii], bf[j], acc[ii][j], 0, 0, 0);
        __builtin_amdgcn_s_setprio(0);
        __builtin_amdgcn_s_barrier();
#pragma unroll
        for (int ii = 0; ii < 4; ++ii)
            af[ii] = *(const short8_t*)(base + 8192 + ii * 1024 + aoff);
        if (tt + 2 < NT) { STG(gA, 0, 0, tt + 2); STG(gB, 16384, 0, tt + 2); }
        __builtin_amdgcn_s_barrier();
        asm volatile("s_waitcnt lgkmcnt(0)" ::: "memory");
        __builtin_amdgcn_sched_barrier(0);
        __builtin_amdgcn_s_setprio(1);
#pragma unroll
        for (int ii = 0; ii < 4; ++ii)
#pragma unroll
            for (int j = 0; j < 4; ++j)
                acc[4 + ii][j] = __builtin_amdgcn_mfma_f32_16x16x32_bf16(
                    af[ii], bf[j], acc[4 + ii][j], 0, 0, 0);
        __builtin_amdgcn_s_setprio(0);
        if (last2) {
            asm volatile("s_waitcnt vmcnt(0)" ::: "memory");
        } else {
            asm volatile("s_waitcnt vmcnt(2)" ::: "memory");   // counted, never 0
        }
        __builtin_amdgcn_sched_barrier(0);
        __builtin_amdgcn_s_barrier();
    };

    for (int t = 0; t + 2 < NT; t += 2) { do_tile(t, false); do_tile(t + 1, false); }
    do_tile(NT - 2, true);
    do_tile(NT - 1, false);
#undef STG

    float* orow = out + (size_t)(m0 + wm + quad * 4) * N + (n0 + wn + l16);
#pragma unroll
    for (int i = 0; i < 8; ++i)
#pragma unroll
        for (int j = 0; j < 4; ++j)
#pragma unroll
            for (int rg = 0; rg < 4; ++rg)
                orow[(size_t)(i * 16 + rg) * N + j * 16] = acc[i][j][rg];
}

// ---------------- launch ----------------
extern "C" void kernel_launch(void* const* d_in, const int* in_sizes, int n_in,
                              void* d_out, int out_size, void* d_ws, size_t ws_size,
                              hipStream_t stream)
{
    const int*   idx   = (const int*)d_in[0];
    const float* wte   = (const float*)d_in[1];
    const float* wpe   = (const float*)d_in[2];
    const float* ln1_a = (const float*)d_in[3];
    const float* ln1_w = (const float*)d_in[4];
    const float* ln1_b = (const float*)d_in[5];
    const float* wq    = (const float*)d_in[6];
    const float* wk    = (const float*)d_in[7];
    const float* wv    = (const float*)d_in[8];
    const float* wo    = (const float*)d_in[9];
    const float* bo    = (const float*)d_in[10];
    const float* ln2_a = (const float*)d_in[11];
    const float* ln2_w = (const float*)d_in[12];
    const float* ln2_b = (const float*)d_in[13];
    const float* w_fc  = (const float*)d_in[14];
    const float* b_fc  = (const float*)d_in[15];
    const float* w_pr  = (const float*)d_in[16];
    const float* b_pr  = (const float*)d_in[17];
    const float* lnf_a = (const float*)d_in[18];
    const float* lnf_w = (const float*)d_in[19];
    const float* lnf_b = (const float*)d_in[20];
    float* out = (float*)d_out;

    char* ws = (char*)d_ws;
    size_t off = 0;
    auto alloc = [&](size_t bytes) -> char* {
        char* p = ws + off;
        off += (bytes + 255) & ~(size_t)255;
        return p;
    };
    __hip_bfloat16* wqkv_t = (__hip_bfloat16*)alloc((size_t)L_ * QKVN_ * D_ * 2);
    __hip_bfloat16* wo_t   = (__hip_bfloat16*)alloc((size_t)L_ * D_ * D_ * 2);
    __hip_bfloat16* wfc_t  = (__hip_bfloat16*)alloc((size_t)L_ * FF_ * D_ * 2);
    __hip_bfloat16* wpr_t  = (__hip_bfloat16*)alloc((size_t)L_ * D_ * FF_ * 2);
    __hip_bfloat16* wte_b  = (__hip_bfloat16*)alloc((size_t)V_ * D_ * 2);
    float*          x      = (float*)alloc((size_t)M_ * D_ * 4);
    __hip_bfloat16* h      = (__hip_bfloat16*)alloc((size_t)M_ * D_ * 2);
    __hip_bfloat16* qkv    = (__hip_bfloat16*)alloc((size_t)M_ * QKVN_ * 2);
    __hip_bfloat16* attno  = (__hip_bfloat16*)alloc((size_t)M_ * D_ * 2);
    __hip_bfloat16* mid    = (__hip_bfloat16*)alloc((size_t)M_ * FF_ * 2);
    (void)ws_size; (void)in_sizes; (void)n_in; (void)out_size;

    // ---- weight prep (bf16, [N,K] layout) ----
    {
        size_t n = (size_t)V_ * D_;
        convert_kernel<<<dim3((unsigned)(n / 1024)), 256, 0, stream>>>(wte, wte_b, n);
    }
    size_t wstride = (size_t)D_ * D_;
    tconv_kernel<<<dim3(24, 24, L_), 256, 0, stream>>>(wq, wqkv_t + 0,            D_, D_, wstride, (size_t)QKVN_ * D_);
    tconv_kernel<<<dim3(24, 24, L_), 256, 0, stream>>>(wk, wqkv_t + (size_t)D_ * D_,   D_, D_, wstride, (size_t)QKVN_ * D_);
    tconv_kernel<<<dim3(24, 24, L_), 256, 0, stream>>>(wv, wqkv_t + (size_t)2 * D_ * D_, D_, D_, wstride, (size_t)QKVN_ * D_);
    tconv_kernel<<<dim3(24, 24, L_), 256, 0, stream>>>(wo, wo_t,                  D_, D_, wstride, wstride);
    tconv_kernel<<<dim3(96, 24, L_), 256, 0, stream>>>(w_fc, wfc_t, D_, FF_, (size_t)D_ * FF_, (size_t)FF_ * D_);
    tconv_kernel<<<dim3(24, 96, L_), 256, 0, stream>>>(w_pr, wpr_t, FF_, D_, (size_t)FF_ * D_, (size_t)D_ * FF_);

    // ---- embedding ----
    embed_kernel<<<dim3(M_), 256, 0, stream>>>(idx, wte, wpe, x);

    // ---- transformer layers ----
    for (int l = 0; l < L_; ++l) {
        dyt_kernel<<<dim3(M_), 256, 0, stream>>>(x, h, ln1_w + l * D_, ln1_b + l * D_, ln1_a + l);
        gemm_btp<0><<<dim3(QKVN_ / 128, M_ / 128), 256, 0, stream>>>(
            h, wqkv_t + (size_t)l * QKVN_ * D_, nullptr, qkv, nullptr, nullptr, M_, QKVN_, D_);
        fattn_kernel<<<dim3(T_ / 64, H_, B_), 256, 0, stream>>>(qkv, attno);
        gemm_btp<1><<<dim3(D_ / 128, M_ / 128), 256, 0, stream>>>(
            attno, wo_t + (size_t)l * D_ * D_, x, nullptr, bo + l * D_, x, M_, D_, D_);
        dyt_kernel<<<dim3(M_), 256, 0, stream>>>(x, h, ln2_w + l * D_, ln2_b + l * D_, ln2_a + l);
        gemm_btp<2><<<dim3(FF_ / 128, M_ / 128), 256, 0, stream>>>(
            h, wfc_t + (size_t)l * FF_ * D_, nullptr, mid, b_fc + l * FF_, nullptr, M_, FF_, D_);
        gemm_btp<1><<<dim3(D_ / 128, M_ / 128), 256, 0, stream>>>(
            mid, wpr_t + (size_t)l * D_ * FF_, x, nullptr, b_pr + l * D_, x, M_, D_, FF_);
    }

    // ---- final DyT + lm_head (256x256 phase-pipelined) ----
    dyt_kernel<<<dim3(M_), 256, 0, stream>>>(x, h, lnf_w, lnf_b, lnf_a);
    gemm_lmhead<<<dim3((M_ / 256) * (V_ / 256)), 512, 0, stream>>>(h, wte_b, out);
}

// Round 5
// 1113.863 us; speedup vs baseline: 1.1728x; 1.0108x over previous
//
#include <hip/hip_runtime.h>
#include <hip/hip_bf16.h>
#include <math.h>

// ---------------- problem constants ----------------
constexpr int B_ = 2, T_ = 1024, D_ = 768, H_ = 12, L_ = 4, V_ = 32000;
constexpr int M_ = B_ * T_;          // 2048 token rows
constexpr int FF_ = 4 * D_;          // 3072
constexpr int QKVN_ = 3 * D_;        // 2304
#define EMB_SCALE 27.712812921102035f
#define EPS_ 1e-5f

typedef __attribute__((ext_vector_type(8))) short short8_t;
typedef __attribute__((ext_vector_type(4))) float float4_t;

__device__ __forceinline__ float bf2f(__hip_bfloat16 v) { return __bfloat162float(v); }
__device__ __forceinline__ __hip_bfloat16 f2bf(float v) { return __float2bfloat16(v); }

// async global->LDS, 16B per lane; lds dest is wave-uniform base + lane*16
__device__ __forceinline__ void gl_lds16(const __hip_bfloat16* g, __hip_bfloat16* l) {
    __builtin_amdgcn_global_load_lds(
        (const __attribute__((address_space(1))) void*)g,
        (__attribute__((address_space(3))) void*)l, 16, 0, 0);
}

// ---------------- weight convert (plain f32 -> bf16) ----------------
__global__ __launch_bounds__(256) void convert_kernel(
    const float* __restrict__ src, __hip_bfloat16* __restrict__ dst, size_t n)
{
    size_t i = ((size_t)blockIdx.x * 256 + threadIdx.x) * 4;
    if (i + 3 < n) {
        float4 f = *(const float4*)(src + i);
        dst[i + 0] = f2bf(f.x);
        dst[i + 1] = f2bf(f.y);
        dst[i + 2] = f2bf(f.z);
        dst[i + 3] = f2bf(f.w);
    }
}

// ------------- transpose + convert: src f32 [K,N] -> dst bf16 [N,K] -------------
__global__ __launch_bounds__(256) void tconv_kernel(
    const float* __restrict__ src, __hip_bfloat16* __restrict__ dst,
    int K, int N, size_t sstride, size_t dstride)
{
    __shared__ float tile[32][33];
    const float* S = src + (size_t)blockIdx.z * sstride;
    __hip_bfloat16* Dd = dst + (size_t)blockIdx.z * dstride;
    int n0 = blockIdx.x * 32, k0 = blockIdx.y * 32;
    int tx = threadIdx.x & 31, ty = threadIdx.x >> 5; // 32 x 8
#pragma unroll
    for (int i = 0; i < 32; i += 8)
        tile[ty + i][tx] = S[(size_t)(k0 + ty + i) * N + n0 + tx];
    __syncthreads();
#pragma unroll
    for (int i = 0; i < 32; i += 8)
        Dd[(size_t)(n0 + ty + i) * K + k0 + tx] = f2bf(tile[tx][ty + i]);
}

// ------------- fused q/k/v/o transpose-convert: z = layer*4 + which -------------
__global__ __launch_bounds__(256) void tconv_qkvo_kernel(
    const float* __restrict__ wq, const float* __restrict__ wk,
    const float* __restrict__ wv, const float* __restrict__ wo,
    __hip_bfloat16* __restrict__ wqkv_t, __hip_bfloat16* __restrict__ wo_t)
{
    __shared__ float tile[32][33];
    const int z = blockIdx.z, l = z >> 2, which = z & 3;
    const size_t dd = (size_t)D_ * D_;
    const float* S = (which == 0 ? wq : which == 1 ? wk : which == 2 ? wv : wo) + (size_t)l * dd;
    __hip_bfloat16* Dd = (which < 3) ? wqkv_t + (size_t)l * QKVN_ * D_ + (size_t)which * dd
                                     : wo_t + (size_t)l * dd;
    int n0 = blockIdx.x * 32, k0 = blockIdx.y * 32;
    int tx = threadIdx.x & 31, ty = threadIdx.x >> 5; // 32 x 8
#pragma unroll
    for (int i = 0; i < 32; i += 8)
        tile[ty + i][tx] = S[(size_t)(k0 + ty + i) * D_ + n0 + tx];
    __syncthreads();
#pragma unroll
    for (int i = 0; i < 32; i += 8)
        Dd[(size_t)(n0 + ty + i) * D_ + k0 + tx] = f2bf(tile[tx][ty + i]);
}

// ---------------- DynamicTanh (optionally fused with embedding) ----------------
template <bool EMBED>
__global__ __launch_bounds__(256) void dyt_kernel(
    const float* __restrict__ xin, float* __restrict__ xout,
    __hip_bfloat16* __restrict__ h,
    const float* __restrict__ w, const float* __restrict__ bb,
    const float* __restrict__ alpha_p,
    const int* __restrict__ idx, const float* __restrict__ wte,
    const float* __restrict__ wpe)
{
    const int row = blockIdx.x, tid = threadIdx.x;
    float v[3];
    float s = 0.f, ss = 0.f;
    if (EMBED) {
        const int t = row & (T_ - 1);
        const int tok = idx[row];
#pragma unroll
        for (int i = 0; i < 3; ++i) {
            int c = i * 256 + tid;
            v[i] = (wte[(size_t)tok * D_ + c] + wpe[(size_t)t * D_ + c]) * EMB_SCALE;
            xout[(size_t)row * D_ + c] = v[i];
            s += v[i];
            ss += v[i] * v[i];
        }
    } else {
        const float* xr = xin + (size_t)row * D_;
#pragma unroll
        for (int i = 0; i < 3; ++i) {
            v[i] = xr[i * 256 + tid];
            s += v[i];
            ss += v[i] * v[i];
        }
    }
#pragma unroll
    for (int off = 32; off >= 1; off >>= 1) {
        s  += __shfl_xor(s,  off, 64);
        ss += __shfl_xor(ss, off, 64);
    }
    __shared__ float sh[8];
    int wave = tid >> 6;
    if ((tid & 63) == 0) { sh[wave] = s; sh[wave + 4] = ss; }
    __syncthreads();
    s  = sh[0] + sh[1] + sh[2] + sh[3];
    ss = sh[4] + sh[5] + sh[6] + sh[7];
    float mu = s * (1.f / D_);
    float var = ss * (1.f / D_) - mu * mu;
    float rstd = rsqrtf(var + EPS_);
    float alpha = *alpha_p;
#pragma unroll
    for (int i = 0; i < 3; ++i) {
        int c = i * 256 + tid;
        float xn = (v[i] - mu) * rstd;
        h[(size_t)row * D_ + c] = f2bf(w[c] * tanhf(alpha * xn) + bb[c]);
    }
}

// ---------------- flash attention: 256 thr, 4 waves, Q-tile 64 rows ----------------
// qkv rows [M, 2304]: q at +0, k at +768, v at +1536. o rows [M, 768].
constexpr int LSTR = 72;   // LDS row stride (elements); 144 B, 16B-aligned rows

__global__ __launch_bounds__(256) void fattn_kernel(
    const __hip_bfloat16* __restrict__ qkv, __hip_bfloat16* __restrict__ o)
{
    const int qt = gridDim.x - 1 - blockIdx.x;   // longest blocks first
    const int hh = blockIdx.y, b = blockIdx.z;
    const int q0 = qt * 64;
    const int tid = threadIdx.x;
    const int wave = tid >> 6, lane = tid & 63;
    const int quad = lane >> 4, l16 = lane & 15;
    const size_t rs = QKVN_;

    __shared__ __hip_bfloat16 Ks[64 * LSTR];      // [k][d]
    __shared__ __hip_bfloat16 Vts[64 * LSTR];     // [d][k] (transposed)
    __shared__ __hip_bfloat16 Ps[4][16 * LSTR];   // per-wave P strip [m][k]

    // Q A-frags: rows q0 + wave*16 + l16, d chunks quad*8 (+32)
    const __hip_bfloat16* qrow = qkv + (size_t)(b * T_ + q0 + wave * 16 + l16) * rs + hh * 64;
    short8_t qf0 = *(const short8_t*)(qrow + quad * 8);
    short8_t qf1 = *(const short8_t*)(qrow + 32 + quad * 8);

    float4_t Oacc[4];
#pragma unroll
    for (int j = 0; j < 4; ++j) Oacc[j] = (float4_t){0.f, 0.f, 0.f, 0.f};
    float mrow[4], lrow[4];
#pragma unroll
    for (int r = 0; r < 4; ++r) { mrow[r] = -1e30f; lrow[r] = 0.f; }

    const __hip_bfloat16* kbase = qkv + (size_t)b * T_ * rs + D_ + hh * 64;
    const __hip_bfloat16* vbase = qkv + (size_t)b * T_ * rs + 2 * D_ + hh * 64;

    const int sr = tid >> 2;            // K staging: row 0..63
    const int sc = (tid & 3) * 8;       // K staging: d chunk
    const int vr = lane;                // V staging: row (k)
    const int vc0 = wave * 16;          // V staging: d chunk start

    for (int kt = 0; kt <= qt; ++kt) {
        const int kt0 = kt * 64;
        uint4 kv0 = *(const uint4*)(kbase + (size_t)(kt0 + sr) * rs + sc);
        uint4 kv1 = *(const uint4*)(kbase + (size_t)(kt0 + sr) * rs + sc + 32);
        uint4 vv0 = *(const uint4*)(vbase + (size_t)(kt0 + vr) * rs + vc0);
        uint4 vv1 = *(const uint4*)(vbase + (size_t)(kt0 + vr) * rs + vc0 + 8);
        __syncthreads();   // WAR: prev tile's frag reads done
        *(uint4*)(Ks + sr * LSTR + sc)      = kv0;
        *(uint4*)(Ks + sr * LSTR + sc + 32) = kv1;
        {
            const __hip_bfloat16* vp = (const __hip_bfloat16*)&vv0;
#pragma unroll
            for (int i = 0; i < 8; ++i) Vts[(vc0 + i) * LSTR + vr] = vp[i];
            vp = (const __hip_bfloat16*)&vv1;
#pragma unroll
            for (int i = 0; i < 8; ++i) Vts[(vc0 + 8 + i) * LSTR + vr] = vp[i];
        }
        __syncthreads();

        // ---- S strip = Q(16) x K^T(64) ----
        float4_t S[4];
#pragma unroll
        for (int jt = 0; jt < 4; ++jt) {
            short8_t kf0 = *(const short8_t*)(Ks + (jt * 16 + l16) * LSTR + quad * 8);
            short8_t kf1 = *(const short8_t*)(Ks + (jt * 16 + l16) * LSTR + 32 + quad * 8);
            float4_t s = (float4_t){0.f, 0.f, 0.f, 0.f};
            s = __builtin_amdgcn_mfma_f32_16x16x32_bf16(qf0, kf0, s, 0, 0, 0);
            s = __builtin_amdgcn_mfma_f32_16x16x32_bf16(qf1, kf1, s, 0, 0, 0);
            S[jt] = s;
        }

        // ---- scale + causal mask (diag tile only) ----
        if (kt == qt) {
#pragma unroll
            for (int jt = 0; jt < 4; ++jt)
#pragma unroll
                for (int r = 0; r < 4; ++r) {
                    int qg = wave * 16 + quad * 4 + r;
                    int kg = jt * 16 + l16;
                    S[jt][r] = (kg > qg) ? -1e30f : S[jt][r] * 0.125f;
                }
        } else {
#pragma unroll
            for (int jt = 0; jt < 4; ++jt)
#pragma unroll
                for (int r = 0; r < 4; ++r) S[jt][r] *= 0.125f;
        }

        // ---- online softmax (rows = quad*4+r, reduce across 16-lane group) ----
        float mnew[4], alphav[4];
#pragma unroll
        for (int r = 0; r < 4; ++r) {
            float mx = fmaxf(fmaxf(S[0][r], S[1][r]), fmaxf(S[2][r], S[3][r]));
            mx = fmaxf(mx, __shfl_xor(mx, 1, 64));
            mx = fmaxf(mx, __shfl_xor(mx, 2, 64));
            mx = fmaxf(mx, __shfl_xor(mx, 4, 64));
            mx = fmaxf(mx, __shfl_xor(mx, 8, 64));
            mnew[r] = fmaxf(mrow[r], mx);
            alphav[r] = __expf(mrow[r] - mnew[r]);
            mrow[r] = mnew[r];
        }
        float psum[4] = {0.f, 0.f, 0.f, 0.f};
#pragma unroll
        for (int jt = 0; jt < 4; ++jt)
#pragma unroll
            for (int r = 0; r < 4; ++r) {
                float p = __expf(S[jt][r] - mnew[r]);
                S[jt][r] = p;
                psum[r] += p;
            }
#pragma unroll
        for (int r = 0; r < 4; ++r) {
            float ps = psum[r];
            ps += __shfl_xor(ps, 1, 64);
            ps += __shfl_xor(ps, 2, 64);
            ps += __shfl_xor(ps, 4, 64);
            ps += __shfl_xor(ps, 8, 64);
            lrow[r] = lrow[r] * alphav[r] + ps;
        }

        // ---- P strip: C-layout regs -> LDS [m][k] (own wave only, no barrier) ----
        __hip_bfloat16* ps_base = Ps[wave];
#pragma unroll
        for (int jt = 0; jt < 4; ++jt)
#pragma unroll
            for (int r = 0; r < 4; ++r)
                ps_base[(quad * 4 + r) * LSTR + jt * 16 + l16] = f2bf(S[jt][r]);

        // ---- rescale O, then O += P @ V ----
#pragma unroll
        for (int j = 0; j < 4; ++j)
#pragma unroll
            for (int r = 0; r < 4; ++r) Oacc[j][r] *= alphav[r];

        short8_t pf0 = *(const short8_t*)(ps_base + l16 * LSTR + quad * 8);
        short8_t pf1 = *(const short8_t*)(ps_base + l16 * LSTR + 32 + quad * 8);
#pragma unroll
        for (int j = 0; j < 4; ++j) {
            short8_t vf0 = *(const short8_t*)(Vts + (j * 16 + l16) * LSTR + quad * 8);
            short8_t vf1 = *(const short8_t*)(Vts + (j * 16 + l16) * LSTR + 32 + quad * 8);
            Oacc[j] = __builtin_amdgcn_mfma_f32_16x16x32_bf16(pf0, vf0, Oacc[j], 0, 0, 0);
            Oacc[j] = __builtin_amdgcn_mfma_f32_16x16x32_bf16(pf1, vf1, Oacc[j], 0, 0, 0);
        }
    }

    // ---- epilogue: O /= l, write ----
    float inv_l[4];
#pragma unroll
    for (int r = 0; r < 4; ++r) inv_l[r] = 1.f / lrow[r];
    __hip_bfloat16* orow = o + (size_t)(b * T_ + q0 + wave * 16) * D_ + hh * 64;
#pragma unroll
    for (int j = 0; j < 4; ++j)
#pragma unroll
        for (int r = 0; r < 4; ++r)
            orow[(size_t)(quad * 4 + r) * D_ + j * 16 + l16] = f2bf(Oacc[j][r] * inv_l[r]);
}

// ---------------- pipelined GEMM: C[M,N] = A[M,K] @ Bt[N,K]^T, 128x128 tile ----------------
// Ring-4 LDS buffers (4 x 16KB), prefetch distance 3, ONE barrier + counted vmcnt per
// K-step. Granule XOR-swizzle (src-preswizzled, swizzled ds_read). Verified round 4.
__device__ __forceinline__ float gelu_exact(float t) {
    return 0.5f * t * (1.0f + erff(t * 0.70710678118654752f));
}

template <int EPI>
__global__ __launch_bounds__(256, 2) void gemm_btp(
    const __hip_bfloat16* __restrict__ A, const __hip_bfloat16* __restrict__ Bt,
    float* __restrict__ outF, __hip_bfloat16* __restrict__ outB,
    const float* __restrict__ bias, const float* __restrict__ res,
    int M, int N, int K)
{
    __shared__ __hip_bfloat16 lds[4 * 8192];   // 4 ring buffers x (A 8KB + B 8KB)
    const int tid = threadIdx.x;
    const int wave = tid >> 6, lane = tid & 63;
    const int quad = lane >> 4, l16 = lane & 15;
    const int m0 = blockIdx.y * 128, n0 = blockIdx.x * 128;
    const int wm = (wave >> 1) * 64, wn = (wave & 1) * 64;
    const int NT = K >> 5;   // K-tiles of 32 (all call sites >= 3)

    const int srow = tid >> 2;                          // 0..63
    const int sq   = (tid & 3) ^ ((srow >> 1) & 3);     // src granule (inverse swizzle)
    const __hip_bfloat16* gA = A  + (size_t)(m0 + srow) * K + sq * 8;
    const __hip_bfloat16* gB = Bt + (size_t)(n0 + srow) * K + sq * 8;
    char* ldsc = (char*)lds;
    const int wb = wave * 1024;   // this wave's 1KB within each 4KB stage chunk

#define STGP(tt) do {                                                      \
        const size_t ko = (size_t)(tt) * 32;                               \
        char* bb = ldsc + ((tt) & 3) * 16384 + wb;                         \
        gl_lds16(gA + ko,                  (__hip_bfloat16*)(bb));         \
        gl_lds16(gA + (size_t)64 * K + ko, (__hip_bfloat16*)(bb + 4096));  \
        gl_lds16(gB + ko,                  (__hip_bfloat16*)(bb + 8192));  \
        gl_lds16(gB + (size_t)64 * K + ko, (__hip_bfloat16*)(bb + 12288)); \
    } while (0)

    const int xe = (quad ^ ((l16 >> 1) & 3)) * 16;

    float4_t acc[4][4];
#pragma unroll
    for (int i = 0; i < 4; ++i)
#pragma unroll
        for (int j = 0; j < 4; ++j) acc[i][j] = (float4_t){0.f, 0.f, 0.f, 0.f};

    STGP(0); STGP(1); STGP(2);
    asm volatile("s_waitcnt vmcnt(8)" ::: "memory");
    __builtin_amdgcn_sched_barrier(0);
    __builtin_amdgcn_s_barrier();

    for (int t = 0; t < NT; ++t) {
        if (t + 3 < NT) STGP(t + 3);
        const char* base = ldsc + (t & 3) * 16384;
        short8_t af[4], bfv[4];
#pragma unroll
        for (int i = 0; i < 4; ++i)
            af[i]  = *(const short8_t*)(base + (wm + i * 16 + l16) * 64 + xe);
#pragma unroll
        for (int j = 0; j < 4; ++j)
            bfv[j] = *(const short8_t*)(base + 8192 + (wn + j * 16 + l16) * 64 + xe);
        asm volatile("s_waitcnt lgkmcnt(0)" ::: "memory");
        __builtin_amdgcn_sched_barrier(0);
        __builtin_amdgcn_s_setprio(1);
#pragma unroll
        for (int i = 0; i < 4; ++i)
#pragma unroll
            for (int j = 0; j < 4; ++j)
                acc[i][j] = __builtin_amdgcn_mfma_f32_16x16x32_bf16(
                    af[i], bfv[j], acc[i][j], 0, 0, 0);
        __builtin_amdgcn_s_setprio(0);
        if (t + 3 < NT) {
            asm volatile("s_waitcnt vmcnt(8)" ::: "memory");
        } else if (t + 2 < NT) {
            asm volatile("s_waitcnt vmcnt(4)" ::: "memory");
        } else if (t + 1 < NT) {
            asm volatile("s_waitcnt vmcnt(0)" ::: "memory");
        }
        __builtin_amdgcn_sched_barrier(0);
        __builtin_amdgcn_s_barrier();
    }
#undef STGP

#pragma unroll
    for (int i = 0; i < 4; ++i) {
#pragma unroll
        for (int j = 0; j < 4; ++j) {
            int colg = n0 + wn + j * 16 + l16;
#pragma unroll
            for (int rg = 0; rg < 4; ++rg) {
                int rowg = m0 + wm + i * 16 + quad * 4 + rg;
                size_t offo = (size_t)rowg * N + colg;
                float v = acc[i][j][rg];
                if (EPI == 0) {
                    outB[offo] = f2bf(v);
                } else if (EPI == 1) {
                    outF[offo] = res[offo] + v + bias[colg];
                } else if (EPI == 2) {
                    outB[offo] = f2bf(gelu_exact(v + bias[colg]));
                } else {
                    outF[offo] = v;
                }
            }
        }
    }
}

// ---------------- lm_head GEMM: 256x256 tile, 8 waves, ring-4 pipelined ----------------
// C[2048, 32000] f32 = A[2048,768] @ Bt[32000,768]^T.
// Same ledger as gemm_btp (verified round 4): ring-4 tile buffers (4 x 32KB = 128 KiB),
// prefetch distance 3, ONE barrier + counted vmcnt(8)/4/0 per K-tile. Per tile:
// 12 ds_read_b128 + 32 MFMA per wave. Granule XOR-swizzle, XCD-chunked m-fast grid.
__global__ __launch_bounds__(512, 2) void gemm_lmhead(
    const __hip_bfloat16* __restrict__ A, const __hip_bfloat16* __restrict__ Bt,
    float* __restrict__ out)
{
    constexpr int K = D_;        // 768
    constexpr int N = V_;        // 32000
    constexpr int NT = K / 32;   // 24 K-tiles
    __shared__ __hip_bfloat16 lds[4 * 16384];   // 4 ring buffers x 32 KB = 128 KiB

    const int tid  = threadIdx.x;
    const int wave = tid >> 6, lane = tid & 63;
    const int quad = lane >> 4, l16 = lane & 15;

    // XCD-chunked, m-fast tile order (bijective: 1000 = 8 * 125)
    const int flat = blockIdx.x;                 // 0..999
    const int g = (flat & 7) * 125 + (flat >> 3);
    const int m0 = (g & 7) * 256, n0 = (g >> 3) * 256;

    const int wm = (wave >> 2) * 128;            // 2 waves in M
    const int wn = (wave & 3) * 64;              // 4 waves in N

    // stage mapping: row srow (0..127) per 128-row chunk, pre-swizzled src k-granule
    const int srow = tid >> 2;
    const int sq   = (tid & 3) ^ ((srow >> 1) & 3);
    const __hip_bfloat16* gA = A  + (size_t)(m0 + srow) * K + sq * 8;
    const __hip_bfloat16* gB = Bt + (size_t)(n0 + srow) * K + sq * 8;
    char* ldsc = (char*)lds;
    const int wb = wave * 1024;   // this wave's 1KB within each 8KB stage chunk

    // one STGP = 4 gl_lds x 512 thr x 16B = 32KB tile:
    // A rows 0-127, 128-255 at buf+0/+8192; B rows 0-127, 128-255 at +16384/+24576
#define STGP(tt) do {                                                        \
        const size_t ko = (size_t)(tt) * 32;                                 \
        char* bb = ldsc + ((tt) & 3) * 32768 + wb;                           \
        gl_lds16(gA + ko,                   (__hip_bfloat16*)(bb));          \
        gl_lds16(gA + (size_t)128 * K + ko, (__hip_bfloat16*)(bb + 8192));   \
        gl_lds16(gB + ko,                   (__hip_bfloat16*)(bb + 16384));  \
        gl_lds16(gB + (size_t)128 * K + ko, (__hip_bfloat16*)(bb + 24576));  \
    } while (0)

    // swizzled ds_read: row r (16-aligned base + l16), granule q at slot q^((r>>1)&3)
    const int xe = (quad ^ ((l16 >> 1) & 3)) * 16;

    float4_t acc[8][4];
#pragma unroll
    for (int i = 0; i < 8; ++i)
#pragma unroll
        for (int j = 0; j < 4; ++j) acc[i][j] = (float4_t){0.f, 0.f, 0.f, 0.f};

    // ---- prologue: tiles 0,1,2 in flight; wait tile 0 (8 loads outstanding) ----
    STGP(0); STGP(1); STGP(2);
    asm volatile("s_waitcnt vmcnt(8)" ::: "memory");
    __builtin_amdgcn_sched_barrier(0);
    __builtin_amdgcn_s_barrier();

    for (int t = 0; t < NT; ++t) {
        if (t + 3 < NT) STGP(t + 3);   // WAR vs buf[(t-1)&3] safe: barrier crossed
        const char* base = ldsc + (t & 3) * 32768;
        short8_t af[8], bfv[4];
#pragma unroll
        for (int i = 0; i < 8; ++i)
            af[i]  = *(const short8_t*)(base + (wm + i * 16 + l16) * 64 + xe);
#pragma unroll
        for (int j = 0; j < 4; ++j)
            bfv[j] = *(const short8_t*)(base + 16384 + (wn + j * 16 + l16) * 64 + xe);
        asm volatile("s_waitcnt lgkmcnt(0)" ::: "memory");
        __builtin_amdgcn_sched_barrier(0);
        __builtin_amdgcn_s_setprio(1);
#pragma unroll
        for (int i = 0; i < 8; ++i)
#pragma unroll
            for (int j = 0; j < 4; ++j)
                acc[i][j] = __builtin_amdgcn_mfma_f32_16x16x32_bf16(
                    af[i], bfv[j], acc[i][j], 0, 0, 0);
        __builtin_amdgcn_s_setprio(0);
        if (t + 3 < NT) {
            asm volatile("s_waitcnt vmcnt(8)" ::: "memory");
        } else if (t + 2 < NT) {
            asm volatile("s_waitcnt vmcnt(4)" ::: "memory");
        } else if (t + 1 < NT) {
            asm volatile("s_waitcnt vmcnt(0)" ::: "memory");
        }
        __builtin_amdgcn_sched_barrier(0);
        __builtin_amdgcn_s_barrier();
    }
#undef STGP

    // ---- epilogue: f32 store ----
    float* orow = out + (size_t)(m0 + wm + quad * 4) * N + (n0 + wn + l16);
#pragma unroll
    for (int i = 0; i < 8; ++i)
#pragma unroll
        for (int j = 0; j < 4; ++j)
#pragma unroll
            for (int rg = 0; rg < 4; ++rg)
                orow[(size_t)(i * 16 + rg) * N + j * 16] = acc[i][j][rg];
}

// ---------------- launch ----------------
extern "C" void kernel_launch(void* const* d_in, const int* in_sizes, int n_in,
                              void* d_out, int out_size, void* d_ws, size_t ws_size,
                              hipStream_t stream)
{
    const int*   idx   = (const int*)d_in[0];
    const float* wte   = (const float*)d_in[1];
    const float* wpe   = (const float*)d_in[2];
    const float* ln1_a = (const float*)d_in[3];
    const float* ln1_w = (const float*)d_in[4];
    const float* ln1_b = (const float*)d_in[5];
    const float* wq    = (const float*)d_in[6];
    const float* wk    = (const float*)d_in[7];
    const float* wv    = (const float*)d_in[8];
    const float* wo    = (const float*)d_in[9];
    const float* bo    = (const float*)d_in[10];
    const float* ln2_a = (const float*)d_in[11];
    const float* ln2_w = (const float*)d_in[12];
    const float* ln2_b = (const float*)d_in[13];
    const float* w_fc  = (const float*)d_in[14];
    const float* b_fc  = (const float*)d_in[15];
    const float* w_pr  = (const float*)d_in[16];
    const float* b_pr  = (const float*)d_in[17];
    const float* lnf_a = (const float*)d_in[18];
    const float* lnf_w = (const float*)d_in[19];
    const float* lnf_b = (const float*)d_in[20];
    float* out = (float*)d_out;

    char* ws = (char*)d_ws;
    size_t off = 0;
    auto alloc = [&](size_t bytes) -> char* {
        char* p = ws + off;
        off += (bytes + 255) & ~(size_t)255;
        return p;
    };
    __hip_bfloat16* wqkv_t = (__hip_bfloat16*)alloc((size_t)L_ * QKVN_ * D_ * 2);
    __hip_bfloat16* wo_t   = (__hip_bfloat16*)alloc((size_t)L_ * D_ * D_ * 2);
    __hip_bfloat16* wfc_t  = (__hip_bfloat16*)alloc((size_t)L_ * FF_ * D_ * 2);
    __hip_bfloat16* wpr_t  = (__hip_bfloat16*)alloc((size_t)L_ * D_ * FF_ * 2);
    __hip_bfloat16* wte_b  = (__hip_bfloat16*)alloc((size_t)V_ * D_ * 2);
    float*          x      = (float*)alloc((size_t)M_ * D_ * 4);
    __hip_bfloat16* h      = (__hip_bfloat16*)alloc((size_t)M_ * D_ * 2);
    __hip_bfloat16* qkv    = (__hip_bfloat16*)alloc((size_t)M_ * QKVN_ * 2);
    __hip_bfloat16* attno  = (__hip_bfloat16*)alloc((size_t)M_ * D_ * 2);
    __hip_bfloat16* mid    = (__hip_bfloat16*)alloc((size_t)M_ * FF_ * 2);
    (void)ws_size; (void)in_sizes; (void)n_in; (void)out_size;

    // ---- weight prep (bf16, [N,K] layout): 4 dispatches ----
    {
        size_t n = (size_t)V_ * D_;
        convert_kernel<<<dim3((unsigned)(n / 1024)), 256, 0, stream>>>(wte, wte_b, n);
    }
    tconv_qkvo_kernel<<<dim3(24, 24, 4 * L_), 256, 0, stream>>>(
        wq, wk, wv, wo, wqkv_t, wo_t);
    tconv_kernel<<<dim3(96, 24, L_), 256, 0, stream>>>(w_fc, wfc_t, D_, FF_, (size_t)D_ * FF_, (size_t)FF_ * D_);
    tconv_kernel<<<dim3(24, 96, L_), 256, 0, stream>>>(w_pr, wpr_t, FF_, D_, (size_t)FF_ * D_, (size_t)D_ * FF_);

    // ---- embedding fused with layer-0 ln1 DyT ----
    dyt_kernel<true><<<dim3(M_), 256, 0, stream>>>(
        nullptr, x, h, ln1_w, ln1_b, ln1_a, idx, wte, wpe);

    // ---- transformer layers ----
    for (int l = 0; l < L_; ++l) {
        if (l > 0)
            dyt_kernel<false><<<dim3(M_), 256, 0, stream>>>(
                x, nullptr, h, ln1_w + l * D_, ln1_b + l * D_, ln1_a + l,
                nullptr, nullptr, nullptr);
        gemm_btp<0><<<dim3(QKVN_ / 128, M_ / 128), 256, 0, stream>>>(
            h, wqkv_t + (size_t)l * QKVN_ * D_, nullptr, qkv, nullptr, nullptr, M_, QKVN_, D_);
        fattn_kernel<<<dim3(T_ / 64, H_, B_), 256, 0, stream>>>(qkv, attno);
        gemm_btp<1><<<dim3(D_ / 128, M_ / 128), 256, 0, stream>>>(
            attno, wo_t + (size_t)l * D_ * D_, x, nullptr, bo + l * D_, x, M_, D_, D_);
        dyt_kernel<false><<<dim3(M_), 256, 0, stream>>>(
            x, nullptr, h, ln2_w + l * D_, ln2_b + l * D_, ln2_a + l,
            nullptr, nullptr, nullptr);
        gemm_btp<2><<<dim3(FF_ / 128, M_ / 128), 256, 0, stream>>>(
            h, wfc_t + (size_t)l * FF_ * D_, nullptr, mid, b_fc + l * FF_, nullptr, M_, FF_, D_);
        gemm_btp<1><<<dim3(D_ / 128, M_ / 128), 256, 0, stream>>>(
            mid, wpr_t + (size_t)l * D_ * FF_, x, nullptr, b_pr + l * D_, x, M_, D_, FF_);
    }

    // ---- final DyT + lm_head (256x256 ring-4 pipelined) ----
    dyt_kernel<false><<<dim3(M_), 256, 0, stream>>>(
        x, nullptr, h, lnf_w, lnf_b, lnf_a, nullptr, nullptr, nullptr);
    gemm_lmhead<<<dim3((M_ / 256) * (V_ / 256)), 512, 0, stream>>>(h, wte_b, out);
}

// Round 6
// 1060.436 us; speedup vs baseline: 1.2318x; 1.0504x over previous
//
#include <hip/hip_runtime.h>
#include <hip/hip_bf16.h>
#include <math.h>

// ---------------- problem constants ----------------
constexpr int B_ = 2, T_ = 1024, D_ = 768, H_ = 12, L_ = 4, V_ = 32000;
constexpr int M_ = B_ * T_;          // 2048 token rows
constexpr int FF_ = 4 * D_;          // 3072
constexpr int QKVN_ = 3 * D_;        // 2304
#define EMB_SCALE 27.712812921102035f
#define EPS_ 1e-5f

typedef __attribute__((ext_vector_type(8))) short short8_t;
typedef __attribute__((ext_vector_type(4))) float float4_t;

__device__ __forceinline__ float bf2f(__hip_bfloat16 v) { return __bfloat162float(v); }
__device__ __forceinline__ __hip_bfloat16 f2bf(float v) { return __float2bfloat16(v); }

// async global->LDS, 16B per lane; lds dest is wave-uniform base + lane*16
__device__ __forceinline__ void gl_lds16(const __hip_bfloat16* g, __hip_bfloat16* l) {
    __builtin_amdgcn_global_load_lds(
        (const __attribute__((address_space(1))) void*)g,
        (__attribute__((address_space(3))) void*)l, 16, 0, 0);
}

// ---------------- weight convert (plain f32 -> bf16) ----------------
__global__ __launch_bounds__(256) void convert_kernel(
    const float* __restrict__ src, __hip_bfloat16* __restrict__ dst, size_t n)
{
    size_t i = ((size_t)blockIdx.x * 256 + threadIdx.x) * 4;
    if (i + 3 < n) {
        float4 f = *(const float4*)(src + i);
        dst[i + 0] = f2bf(f.x);
        dst[i + 1] = f2bf(f.y);
        dst[i + 2] = f2bf(f.z);
        dst[i + 3] = f2bf(f.w);
    }
}

// ------------- transpose + convert: src f32 [K,N] -> dst bf16 [N,K] -------------
__global__ __launch_bounds__(256) void tconv_kernel(
    const float* __restrict__ src, __hip_bfloat16* __restrict__ dst,
    int K, int N, size_t sstride, size_t dstride)
{
    __shared__ float tile[32][33];
    const float* S = src + (size_t)blockIdx.z * sstride;
    __hip_bfloat16* Dd = dst + (size_t)blockIdx.z * dstride;
    int n0 = blockIdx.x * 32, k0 = blockIdx.y * 32;
    int tx = threadIdx.x & 31, ty = threadIdx.x >> 5; // 32 x 8
#pragma unroll
    for (int i = 0; i < 32; i += 8)
        tile[ty + i][tx] = S[(size_t)(k0 + ty + i) * N + n0 + tx];
    __syncthreads();
#pragma unroll
    for (int i = 0; i < 32; i += 8)
        Dd[(size_t)(n0 + ty + i) * K + k0 + tx] = f2bf(tile[tx][ty + i]);
}

// ------------- fused q/k/v/o transpose-convert: z = layer*4 + which -------------
__global__ __launch_bounds__(256) void tconv_qkvo_kernel(
    const float* __restrict__ wq, const float* __restrict__ wk,
    const float* __restrict__ wv, const float* __restrict__ wo,
    __hip_bfloat16* __restrict__ wqkv_t, __hip_bfloat16* __restrict__ wo_t)
{
    __shared__ float tile[32][33];
    const int z = blockIdx.z, l = z >> 2, which = z & 3;
    const size_t dd = (size_t)D_ * D_;
    const float* S = (which == 0 ? wq : which == 1 ? wk : which == 2 ? wv : wo) + (size_t)l * dd;
    __hip_bfloat16* Dd = (which < 3) ? wqkv_t + (size_t)l * QKVN_ * D_ + (size_t)which * dd
                                     : wo_t + (size_t)l * dd;
    int n0 = blockIdx.x * 32, k0 = blockIdx.y * 32;
    int tx = threadIdx.x & 31, ty = threadIdx.x >> 5; // 32 x 8
#pragma unroll
    for (int i = 0; i < 32; i += 8)
        tile[ty + i][tx] = S[(size_t)(k0 + ty + i) * D_ + n0 + tx];
    __syncthreads();
#pragma unroll
    for (int i = 0; i < 32; i += 8)
        Dd[(size_t)(n0 + ty + i) * D_ + k0 + tx] = f2bf(tile[tx][ty + i]);
}

// ---------------- DynamicTanh (optionally fused with embedding) ----------------
template <bool EMBED>
__global__ __launch_bounds__(256) void dyt_kernel(
    const float* __restrict__ xin, float* __restrict__ xout,
    __hip_bfloat16* __restrict__ h,
    const float* __restrict__ w, const float* __restrict__ bb,
    const float* __restrict__ alpha_p,
    const int* __restrict__ idx, const float* __restrict__ wte,
    const float* __restrict__ wpe)
{
    const int row = blockIdx.x, tid = threadIdx.x;
    float v[3];
    float s = 0.f, ss = 0.f;
    if (EMBED) {
        const int t = row & (T_ - 1);
        const int tok = idx[row];
#pragma unroll
        for (int i = 0; i < 3; ++i) {
            int c = i * 256 + tid;
            v[i] = (wte[(size_t)tok * D_ + c] + wpe[(size_t)t * D_ + c]) * EMB_SCALE;
            xout[(size_t)row * D_ + c] = v[i];
            s += v[i];
            ss += v[i] * v[i];
        }
    } else {
        const float* xr = xin + (size_t)row * D_;
#pragma unroll
        for (int i = 0; i < 3; ++i) {
            v[i] = xr[i * 256 + tid];
            s += v[i];
            ss += v[i] * v[i];
        }
    }
#pragma unroll
    for (int off = 32; off >= 1; off >>= 1) {
        s  += __shfl_xor(s,  off, 64);
        ss += __shfl_xor(ss, off, 64);
    }
    __shared__ float sh[8];
    int wave = tid >> 6;
    if ((tid & 63) == 0) { sh[wave] = s; sh[wave + 4] = ss; }
    __syncthreads();
    s  = sh[0] + sh[1] + sh[2] + sh[3];
    ss = sh[4] + sh[5] + sh[6] + sh[7];
    float mu = s * (1.f / D_);
    float var = ss * (1.f / D_) - mu * mu;
    float rstd = rsqrtf(var + EPS_);
    float alpha = *alpha_p;
#pragma unroll
    for (int i = 0; i < 3; ++i) {
        int c = i * 256 + tid;
        float xn = (v[i] - mu) * rstd;
        h[(size_t)row * D_ + c] = f2bf(w[c] * tanhf(alpha * xn) + bb[c]);
    }
}

// ---------------- flash attention: 256 thr, 4 waves, Q-tile 64 rows ----------------
// qkv rows [M, 2304]: q at +0, k at +768, v at +1536. o rows [M, 768].
// Pipelined staging (T14): tile kt+1's K/V global loads are ISSUED after the
// visibility barrier of tile kt, so the vmcnt(0) drain at the next WAR barrier
// lands after ~600+ cycles of QK/softmax/PV compute (was: issue -> immediate drain).
constexpr int LSTR = 72;   // LDS row stride (elements); 144 B, 16B-aligned rows

__global__ __launch_bounds__(256) void fattn_kernel(
    const __hip_bfloat16* __restrict__ qkv, __hip_bfloat16* __restrict__ o)
{
    const int qt = gridDim.x - 1 - blockIdx.x;   // longest blocks first
    const int hh = blockIdx.y, b = blockIdx.z;
    const int q0 = qt * 64;
    const int tid = threadIdx.x;
    const int wave = tid >> 6, lane = tid & 63;
    const int quad = lane >> 4, l16 = lane & 15;
    const size_t rs = QKVN_;

    __shared__ __hip_bfloat16 Ks[64 * LSTR];      // [k][d]
    __shared__ __hip_bfloat16 Vts[64 * LSTR];     // [d][k] (transposed)
    __shared__ __hip_bfloat16 Ps[4][16 * LSTR];   // per-wave P strip [m][k]

    // Q A-frags: rows q0 + wave*16 + l16, d chunks quad*8 (+32)
    const __hip_bfloat16* qrow = qkv + (size_t)(b * T_ + q0 + wave * 16 + l16) * rs + hh * 64;
    short8_t qf0 = *(const short8_t*)(qrow + quad * 8);
    short8_t qf1 = *(const short8_t*)(qrow + 32 + quad * 8);

    float4_t Oacc[4];
#pragma unroll
    for (int j = 0; j < 4; ++j) Oacc[j] = (float4_t){0.f, 0.f, 0.f, 0.f};
    float mrow[4], lrow[4];
#pragma unroll
    for (int r = 0; r < 4; ++r) { mrow[r] = -1e30f; lrow[r] = 0.f; }

    const __hip_bfloat16* kbase = qkv + (size_t)b * T_ * rs + D_ + hh * 64;
    const __hip_bfloat16* vbase = qkv + (size_t)b * T_ * rs + 2 * D_ + hh * 64;

    const int sr = tid >> 2;            // K staging: row 0..63
    const int sc = (tid & 3) * 8;       // K staging: d chunk
    const int vr = lane;                // V staging: row (k)
    const int vc0 = wave * 16;          // V staging: d chunk start

    // preload tile 0 into regs
    uint4 kv0 = *(const uint4*)(kbase + (size_t)sr * rs + sc);
    uint4 kv1 = *(const uint4*)(kbase + (size_t)sr * rs + sc + 32);
    uint4 vv0 = *(const uint4*)(vbase + (size_t)vr * rs + vc0);
    uint4 vv1 = *(const uint4*)(vbase + (size_t)vr * rs + vc0 + 8);

    for (int kt = 0; kt <= qt; ++kt) {
        __syncthreads();   // WAR: prev tile's frag reads done (drains in-flight loads)
        *(uint4*)(Ks + sr * LSTR + sc)      = kv0;
        *(uint4*)(Ks + sr * LSTR + sc + 32) = kv1;
        {
            const __hip_bfloat16* vp = (const __hip_bfloat16*)&vv0;
#pragma unroll
            for (int i = 0; i < 8; ++i) Vts[(vc0 + i) * LSTR + vr] = vp[i];
            vp = (const __hip_bfloat16*)&vv1;
#pragma unroll
            for (int i = 0; i < 8; ++i) Vts[(vc0 + 8 + i) * LSTR + vr] = vp[i];
        }
        __syncthreads();

        // issue next tile's loads NOW; their wait is next iteration's WAR barrier,
        // ~600+ cycles of compute below covers the L2/HBM latency.
        if (kt < qt) {
            const int kn0 = (kt + 1) * 64;
            kv0 = *(const uint4*)(kbase + (size_t)(kn0 + sr) * rs + sc);
            kv1 = *(const uint4*)(kbase + (size_t)(kn0 + sr) * rs + sc + 32);
            vv0 = *(const uint4*)(vbase + (size_t)(kn0 + vr) * rs + vc0);
            vv1 = *(const uint4*)(vbase + (size_t)(kn0 + vr) * rs + vc0 + 8);
        }

        // ---- S strip = Q(16) x K^T(64) ----
        float4_t S[4];
#pragma unroll
        for (int jt = 0; jt < 4; ++jt) {
            short8_t kf0 = *(const short8_t*)(Ks + (jt * 16 + l16) * LSTR + quad * 8);
            short8_t kf1 = *(const short8_t*)(Ks + (jt * 16 + l16) * LSTR + 32 + quad * 8);
            float4_t s = (float4_t){0.f, 0.f, 0.f, 0.f};
            s = __builtin_amdgcn_mfma_f32_16x16x32_bf16(qf0, kf0, s, 0, 0, 0);
            s = __builtin_amdgcn_mfma_f32_16x16x32_bf16(qf1, kf1, s, 0, 0, 0);
            S[jt] = s;
        }

        // ---- scale + causal mask (diag tile only) ----
        if (kt == qt) {
#pragma unroll
            for (int jt = 0; jt < 4; ++jt)
#pragma unroll
                for (int r = 0; r < 4; ++r) {
                    int qg = wave * 16 + quad * 4 + r;
                    int kg = jt * 16 + l16;
                    S[jt][r] = (kg > qg) ? -1e30f : S[jt][r] * 0.125f;
                }
        } else {
#pragma unroll
            for (int jt = 0; jt < 4; ++jt)
#pragma unroll
                for (int r = 0; r < 4; ++r) S[jt][r] *= 0.125f;
        }

        // ---- online softmax (rows = quad*4+r, reduce across 16-lane group) ----
        float mnew[4], alphav[4];
#pragma unroll
        for (int r = 0; r < 4; ++r) {
            float mx = fmaxf(fmaxf(S[0][r], S[1][r]), fmaxf(S[2][r], S[3][r]));
            mx = fmaxf(mx, __shfl_xor(mx, 1, 64));
            mx = fmaxf(mx, __shfl_xor(mx, 2, 64));
            mx = fmaxf(mx, __shfl_xor(mx, 4, 64));
            mx = fmaxf(mx, __shfl_xor(mx, 8, 64));
            mnew[r] = fmaxf(mrow[r], mx);
            alphav[r] = __expf(mrow[r] - mnew[r]);
            mrow[r] = mnew[r];
        }
        float psum[4] = {0.f, 0.f, 0.f, 0.f};
#pragma unroll
        for (int jt = 0; jt < 4; ++jt)
#pragma unroll
            for (int r = 0; r < 4; ++r) {
                float p = __expf(S[jt][r] - mnew[r]);
                S[jt][r] = p;
                psum[r] += p;
            }
#pragma unroll
        for (int r = 0; r < 4; ++r) {
            float ps = psum[r];
            ps += __shfl_xor(ps, 1, 64);
            ps += __shfl_xor(ps, 2, 64);
            ps += __shfl_xor(ps, 4, 64);
            ps += __shfl_xor(ps, 8, 64);
            lrow[r] = lrow[r] * alphav[r] + ps;
        }

        // ---- P strip: C-layout regs -> LDS [m][k] (own wave only, no barrier) ----
        __hip_bfloat16* ps_base = Ps[wave];
#pragma unroll
        for (int jt = 0; jt < 4; ++jt)
#pragma unroll
            for (int r = 0; r < 4; ++r)
                ps_base[(quad * 4 + r) * LSTR + jt * 16 + l16] = f2bf(S[jt][r]);

        // ---- rescale O, then O += P @ V ----
#pragma unroll
        for (int j = 0; j < 4; ++j)
#pragma unroll
            for (int r = 0; r < 4; ++r) Oacc[j][r] *= alphav[r];

        short8_t pf0 = *(const short8_t*)(ps_base + l16 * LSTR + quad * 8);
        short8_t pf1 = *(const short8_t*)(ps_base + l16 * LSTR + 32 + quad * 8);
#pragma unroll
        for (int j = 0; j < 4; ++j) {
            short8_t vf0 = *(const short8_t*)(Vts + (j * 16 + l16) * LSTR + quad * 8);
            short8_t vf1 = *(const short8_t*)(Vts + (j * 16 + l16) * LSTR + 32 + quad * 8);
            Oacc[j] = __builtin_amdgcn_mfma_f32_16x16x32_bf16(pf0, vf0, Oacc[j], 0, 0, 0);
            Oacc[j] = __builtin_amdgcn_mfma_f32_16x16x32_bf16(pf1, vf1, Oacc[j], 0, 0, 0);
        }
    }

    // ---- epilogue: O /= l, write ----
    float inv_l[4];
#pragma unroll
    for (int r = 0; r < 4; ++r) inv_l[r] = 1.f / lrow[r];
    __hip_bfloat16* orow = o + (size_t)(b * T_ + q0 + wave * 16) * D_ + hh * 64;
#pragma unroll
    for (int j = 0; j < 4; ++j)
#pragma unroll
        for (int r = 0; r < 4; ++r)
            orow[(size_t)(quad * 4 + r) * D_ + j * 16 + l16] = f2bf(Oacc[j][r] * inv_l[r]);
}

// ---------------- pipelined GEMM: C[M,N] = A[M,K] @ Bt[N,K]^T, 128x128 tile ----------------
// Ring-4 LDS buffers (4 x 16KB), prefetch distance 3, ONE barrier + counted vmcnt per
// K-step. Granule XOR-swizzle (src-preswizzled, swizzled ds_read). Verified round 4.
__device__ __forceinline__ float gelu_exact(float t) {
    return 0.5f * t * (1.0f + erff(t * 0.70710678118654752f));
}

template <int EPI>
__global__ __launch_bounds__(256, 2) void gemm_btp(
    const __hip_bfloat16* __restrict__ A, const __hip_bfloat16* __restrict__ Bt,
    float* __restrict__ outF, __hip_bfloat16* __restrict__ outB,
    const float* __restrict__ bias, const float* __restrict__ res,
    int M, int N, int K)
{
    __shared__ __hip_bfloat16 lds[4 * 8192];   // 4 ring buffers x (A 8KB + B 8KB)
    const int tid = threadIdx.x;
    const int wave = tid >> 6, lane = tid & 63;
    const int quad = lane >> 4, l16 = lane & 15;
    const int m0 = blockIdx.y * 128, n0 = blockIdx.x * 128;
    const int wm = (wave >> 1) * 64, wn = (wave & 1) * 64;
    const int NT = K >> 5;   // K-tiles of 32 (all call sites >= 3)

    const int srow = tid >> 2;                          // 0..63
    const int sq   = (tid & 3) ^ ((srow >> 1) & 3);     // src granule (inverse swizzle)
    const __hip_bfloat16* gA = A  + (size_t)(m0 + srow) * K + sq * 8;
    const __hip_bfloat16* gB = Bt + (size_t)(n0 + srow) * K + sq * 8;
    char* ldsc = (char*)lds;
    const int wb = wave * 1024;   // this wave's 1KB within each 4KB stage chunk

#define STGP(tt) do {                                                      \
        const size_t ko = (size_t)(tt) * 32;                               \
        char* bb = ldsc + ((tt) & 3) * 16384 + wb;                         \
        gl_lds16(gA + ko,                  (__hip_bfloat16*)(bb));         \
        gl_lds16(gA + (size_t)64 * K + ko, (__hip_bfloat16*)(bb + 4096));  \
        gl_lds16(gB + ko,                  (__hip_bfloat16*)(bb + 8192));  \
        gl_lds16(gB + (size_t)64 * K + ko, (__hip_bfloat16*)(bb + 12288)); \
    } while (0)

    const int xe = (quad ^ ((l16 >> 1) & 3)) * 16;

    float4_t acc[4][4];
#pragma unroll
    for (int i = 0; i < 4; ++i)
#pragma unroll
        for (int j = 0; j < 4; ++j) acc[i][j] = (float4_t){0.f, 0.f, 0.f, 0.f};

    STGP(0); STGP(1); STGP(2);
    asm volatile("s_waitcnt vmcnt(8)" ::: "memory");
    __builtin_amdgcn_sched_barrier(0);
    __builtin_amdgcn_s_barrier();

    for (int t = 0; t < NT; ++t) {
        if (t + 3 < NT) STGP(t + 3);
        const char* base = ldsc + (t & 3) * 16384;
        short8_t af[4], bfv[4];
#pragma unroll
        for (int i = 0; i < 4; ++i)
            af[i]  = *(const short8_t*)(base + (wm + i * 16 + l16) * 64 + xe);
#pragma unroll
        for (int j = 0; j < 4; ++j)
            bfv[j] = *(const short8_t*)(base + 8192 + (wn + j * 16 + l16) * 64 + xe);
        asm volatile("s_waitcnt lgkmcnt(0)" ::: "memory");
        __builtin_amdgcn_sched_barrier(0);
        __builtin_amdgcn_s_setprio(1);
#pragma unroll
        for (int i = 0; i < 4; ++i)
#pragma unroll
            for (int j = 0; j < 4; ++j)
                acc[i][j] = __builtin_amdgcn_mfma_f32_16x16x32_bf16(
                    af[i], bfv[j], acc[i][j], 0, 0, 0);
        __builtin_amdgcn_s_setprio(0);
        if (t + 3 < NT) {
            asm volatile("s_waitcnt vmcnt(8)" ::: "memory");
        } else if (t + 2 < NT) {
            asm volatile("s_waitcnt vmcnt(4)" ::: "memory");
        } else if (t + 1 < NT) {
            asm volatile("s_waitcnt vmcnt(0)" ::: "memory");
        }
        __builtin_amdgcn_sched_barrier(0);
        __builtin_amdgcn_s_barrier();
    }
#undef STGP

#pragma unroll
    for (int i = 0; i < 4; ++i) {
#pragma unroll
        for (int j = 0; j < 4; ++j) {
            int colg = n0 + wn + j * 16 + l16;
#pragma unroll
            for (int rg = 0; rg < 4; ++rg) {
                int rowg = m0 + wm + i * 16 + quad * 4 + rg;
                size_t offo = (size_t)rowg * N + colg;
                float v = acc[i][j][rg];
                if (EPI == 0) {
                    outB[offo] = f2bf(v);
                } else if (EPI == 1) {
                    outF[offo] = res[offo] + v + bias[colg];
                } else if (EPI == 2) {
                    outB[offo] = f2bf(gelu_exact(v + bias[colg]));
                } else {
                    outF[offo] = v;
                }
            }
        }
    }
}

// ---------------- pipelined GEMM, 64x128 tile (small-N critical-path variant) ----------------
// For fully-co-resident small dispatches (WO/proj: N=768 -> 96 blocks at 128^2), the
// dispatch time = ONE block's K-loop. 64M x 128N halves per-block work -> 192 blocks,
// still co-resident. Same ring-4 ledger, 3 loads/tile: prologue 9, wait 6; loop 6/3/0.
template <int EPI>
__global__ __launch_bounds__(256, 2) void gemm_btp64(
    const __hip_bfloat16* __restrict__ A, const __hip_bfloat16* __restrict__ Bt,
    float* __restrict__ outF, __hip_bfloat16* __restrict__ outB,
    const float* __restrict__ bias, const float* __restrict__ res,
    int M, int N, int K)
{
    __shared__ __hip_bfloat16 lds[4 * 6144];   // 4 ring buffers x (A 4KB + B 8KB)
    const int tid = threadIdx.x;
    const int wave = tid >> 6, lane = tid & 63;
    const int quad = lane >> 4, l16 = lane & 15;
    const int m0 = blockIdx.y * 64, n0 = blockIdx.x * 128;
    const int wm = (wave >> 1) * 32, wn = (wave & 1) * 64;   // 2 waves M x 2 waves N
    const int NT = K >> 5;

    const int srow = tid >> 2;                          // 0..63
    const int sq   = (tid & 3) ^ ((srow >> 1) & 3);     // src granule (inverse swizzle)
    const __hip_bfloat16* gA = A  + (size_t)(m0 + srow) * K + sq * 8;
    const __hip_bfloat16* gB = Bt + (size_t)(n0 + srow) * K + sq * 8;
    char* ldsc = (char*)lds;
    const int wb = wave * 1024;

#define STGP64(tt) do {                                                    \
        const size_t ko = (size_t)(tt) * 32;                               \
        char* bb = ldsc + ((tt) & 3) * 12288 + wb;                         \
        gl_lds16(gA + ko,                  (__hip_bfloat16*)(bb));         \
        gl_lds16(gB + ko,                  (__hip_bfloat16*)(bb + 4096));  \
        gl_lds16(gB + (size_t)64 * K + ko, (__hip_bfloat16*)(bb + 8192));  \
    } while (0)

    const int xe = (quad ^ ((l16 >> 1) & 3)) * 16;

    float4_t acc[2][4];
#pragma unroll
    for (int i = 0; i < 2; ++i)
#pragma unroll
        for (int j = 0; j < 4; ++j) acc[i][j] = (float4_t){0.f, 0.f, 0.f, 0.f};

    STGP64(0); STGP64(1); STGP64(2);
    asm volatile("s_waitcnt vmcnt(6)" ::: "memory");
    __builtin_amdgcn_sched_barrier(0);
    __builtin_amdgcn_s_barrier();

    for (int t = 0; t < NT; ++t) {
        if (t + 3 < NT) STGP64(t + 3);
        const char* base = ldsc + (t & 3) * 12288;
        short8_t af[2], bfv[4];
#pragma unroll
        for (int i = 0; i < 2; ++i)
            af[i]  = *(const short8_t*)(base + (wm + i * 16 + l16) * 64 + xe);
#pragma unroll
        for (int j = 0; j < 4; ++j)
            bfv[j] = *(const short8_t*)(base + 4096 + (wn + j * 16 + l16) * 64 + xe);
        asm volatile("s_waitcnt lgkmcnt(0)" ::: "memory");
        __builtin_amdgcn_sched_barrier(0);
        __builtin_amdgcn_s_setprio(1);
#pragma unroll
        for (int i = 0; i < 2; ++i)
#pragma unroll
            for (int j = 0; j < 4; ++j)
                acc[i][j] = __builtin_amdgcn_mfma_f32_16x16x32_bf16(
                    af[i], bfv[j], acc[i][j], 0, 0, 0);
        __builtin_amdgcn_s_setprio(0);
        if (t + 3 < NT) {
            asm volatile("s_waitcnt vmcnt(6)" ::: "memory");
        } else if (t + 2 < NT) {
            asm volatile("s_waitcnt vmcnt(3)" ::: "memory");
        } else if (t + 1 < NT) {
            asm volatile("s_waitcnt vmcnt(0)" ::: "memory");
        }
        __builtin_amdgcn_sched_barrier(0);
        __builtin_amdgcn_s_barrier();
    }
#undef STGP64

#pragma unroll
    for (int i = 0; i < 2; ++i) {
#pragma unroll
        for (int j = 0; j < 4; ++j) {
            int colg = n0 + wn + j * 16 + l16;
#pragma unroll
            for (int rg = 0; rg < 4; ++rg) {
                int rowg = m0 + wm + i * 16 + quad * 4 + rg;
                size_t offo = (size_t)rowg * N + colg;
                float v = acc[i][j][rg];
                if (EPI == 0) {
                    outB[offo] = f2bf(v);
                } else if (EPI == 1) {
                    outF[offo] = res[offo] + v + bias[colg];
                } else if (EPI == 2) {
                    outB[offo] = f2bf(gelu_exact(v + bias[colg]));
                } else {
                    outF[offo] = v;
                }
            }
        }
    }
}

// ---------------- lm_head GEMM: 256x256 tile, 8 waves, ring-4 pipelined ----------------
// (verified passing round 5 — unchanged)
__global__ __launch_bounds__(512, 2) void gemm_lmhead(
    const __hip_bfloat16* __restrict__ A, const __hip_bfloat16* __restrict__ Bt,
    float* __restrict__ out)
{
    constexpr int K = D_;        // 768
    constexpr int N = V_;        // 32000
    constexpr int NT = K / 32;   // 24 K-tiles
    __shared__ __hip_bfloat16 lds[4 * 16384];   // 4 ring buffers x 32 KB = 128 KiB

    const int tid  = threadIdx.x;
    const int wave = tid >> 6, lane = tid & 63;
    const int quad = lane >> 4, l16 = lane & 15;

    const int flat = blockIdx.x;                 // 0..999
    const int g = (flat & 7) * 125 + (flat >> 3);
    const int m0 = (g & 7) * 256, n0 = (g >> 3) * 256;

    const int wm = (wave >> 2) * 128;            // 2 waves in M
    const int wn = (wave & 3) * 64;              // 4 waves in N

    const int srow = tid >> 2;
    const int sq   = (tid & 3) ^ ((srow >> 1) & 3);
    const __hip_bfloat16* gA = A  + (size_t)(m0 + srow) * K + sq * 8;
    const __hip_bfloat16* gB = Bt + (size_t)(n0 + srow) * K + sq * 8;
    char* ldsc = (char*)lds;
    const int wb = wave * 1024;

#define STGP(tt) do {                                                        \
        const size_t ko = (size_t)(tt) * 32;                                 \
        char* bb = ldsc + ((tt) & 3) * 32768 + wb;                           \
        gl_lds16(gA + ko,                   (__hip_bfloat16*)(bb));          \
        gl_lds16(gA + (size_t)128 * K + ko, (__hip_bfloat16*)(bb + 8192));   \
        gl_lds16(gB + ko,                   (__hip_bfloat16*)(bb + 16384));  \
        gl_lds16(gB + (size_t)128 * K + ko, (__hip_bfloat16*)(bb + 24576));  \
    } while (0)

    const int xe = (quad ^ ((l16 >> 1) & 3)) * 16;

    float4_t acc[8][4];
#pragma unroll
    for (int i = 0; i < 8; ++i)
#pragma unroll
        for (int j = 0; j < 4; ++j) acc[i][j] = (float4_t){0.f, 0.f, 0.f, 0.f};

    STGP(0); STGP(1); STGP(2);
    asm volatile("s_waitcnt vmcnt(8)" ::: "memory");
    __builtin_amdgcn_sched_barrier(0);
    __builtin_amdgcn_s_barrier();

    for (int t = 0; t < NT; ++t) {
        if (t + 3 < NT) STGP(t + 3);
        const char* base = ldsc + (t & 3) * 32768;
        short8_t af[8], bfv[4];
#pragma unroll
        for (int i = 0; i < 8; ++i)
            af[i]  = *(const short8_t*)(base + (wm + i * 16 + l16) * 64 + xe);
#pragma unroll
        for (int j = 0; j < 4; ++j)
            bfv[j] = *(const short8_t*)(base + 16384 + (wn + j * 16 + l16) * 64 + xe);
        asm volatile("s_waitcnt lgkmcnt(0)" ::: "memory");
        __builtin_amdgcn_sched_barrier(0);
        __builtin_amdgcn_s_setprio(1);
#pragma unroll
        for (int i = 0; i < 8; ++i)
#pragma unroll
            for (int j = 0; j < 4; ++j)
                acc[i][j] = __builtin_amdgcn_mfma_f32_16x16x32_bf16(
                    af[i], bfv[j], acc[i][j], 0, 0, 0);
        __builtin_amdgcn_s_setprio(0);
        if (t + 3 < NT) {
            asm volatile("s_waitcnt vmcnt(8)" ::: "memory");
        } else if (t + 2 < NT) {
            asm volatile("s_waitcnt vmcnt(4)" ::: "memory");
        } else if (t + 1 < NT) {
            asm volatile("s_waitcnt vmcnt(0)" ::: "memory");
        }
        __builtin_amdgcn_sched_barrier(0);
        __builtin_amdgcn_s_barrier();
    }
#undef STGP

    float* orow = out + (size_t)(m0 + wm + quad * 4) * N + (n0 + wn + l16);
#pragma unroll
    for (int i = 0; i < 8; ++i)
#pragma unroll
        for (int j = 0; j < 4; ++j)
#pragma unroll
            for (int rg = 0; rg < 4; ++rg)
                orow[(size_t)(i * 16 + rg) * N + j * 16] = acc[i][j][rg];
}

// ---------------- launch ----------------
extern "C" void kernel_launch(void* const* d_in, const int* in_sizes, int n_in,
                              void* d_out, int out_size, void* d_ws, size_t ws_size,
                              hipStream_t stream)
{
    const int*   idx   = (const int*)d_in[0];
    const float* wte   = (const float*)d_in[1];
    const float* wpe   = (const float*)d_in[2];
    const float* ln1_a = (const float*)d_in[3];
    const float* ln1_w = (const float*)d_in[4];
    const float* ln1_b = (const float*)d_in[5];
    const float* wq    = (const float*)d_in[6];
    const float* wk    = (const float*)d_in[7];
    const float* wv    = (const float*)d_in[8];
    const float* wo    = (const float*)d_in[9];
    const float* bo    = (const float*)d_in[10];
    const float* ln2_a = (const float*)d_in[11];
    const float* ln2_w = (const float*)d_in[12];
    const float* ln2_b = (const float*)d_in[13];
    const float* w_fc  = (const float*)d_in[14];
    const float* b_fc  = (const float*)d_in[15];
    const float* w_pr  = (const float*)d_in[16];
    const float* b_pr  = (const float*)d_in[17];
    const float* lnf_a = (const float*)d_in[18];
    const float* lnf_w = (const float*)d_in[19];
    const float* lnf_b = (const float*)d_in[20];
    float* out = (float*)d_out;

    char* ws = (char*)d_ws;
    size_t off = 0;
    auto alloc = [&](size_t bytes) -> char* {
        char* p = ws + off;
        off += (bytes + 255) & ~(size_t)255;
        return p;
    };
    __hip_bfloat16* wqkv_t = (__hip_bfloat16*)alloc((size_t)L_ * QKVN_ * D_ * 2);
    __hip_bfloat16* wo_t   = (__hip_bfloat16*)alloc((size_t)L_ * D_ * D_ * 2);
    __hip_bfloat16* wfc_t  = (__hip_bfloat16*)alloc((size_t)L_ * FF_ * D_ * 2);
    __hip_bfloat16* wpr_t  = (__hip_bfloat16*)alloc((size_t)L_ * D_ * FF_ * 2);
    __hip_bfloat16* wte_b  = (__hip_bfloat16*)alloc((size_t)V_ * D_ * 2);
    float*          x      = (float*)alloc((size_t)M_ * D_ * 4);
    __hip_bfloat16* h      = (__hip_bfloat16*)alloc((size_t)M_ * D_ * 2);
    __hip_bfloat16* qkv    = (__hip_bfloat16*)alloc((size_t)M_ * QKVN_ * 2);
    __hip_bfloat16* attno  = (__hip_bfloat16*)alloc((size_t)M_ * D_ * 2);
    __hip_bfloat16* mid    = (__hip_bfloat16*)alloc((size_t)M_ * FF_ * 2);
    (void)ws_size; (void)in_sizes; (void)n_in; (void)out_size;

    // ---- weight prep (bf16, [N,K] layout): 4 dispatches ----
    {
        size_t n = (size_t)V_ * D_;
        convert_kernel<<<dim3((unsigned)(n / 1024)), 256, 0, stream>>>(wte, wte_b, n);
    }
    tconv_qkvo_kernel<<<dim3(24, 24, 4 * L_), 256, 0, stream>>>(
        wq, wk, wv, wo, wqkv_t, wo_t);
    tconv_kernel<<<dim3(96, 24, L_), 256, 0, stream>>>(w_fc, wfc_t, D_, FF_, (size_t)D_ * FF_, (size_t)FF_ * D_);
    tconv_kernel<<<dim3(24, 96, L_), 256, 0, stream>>>(w_pr, wpr_t, FF_, D_, (size_t)FF_ * D_, (size_t)D_ * FF_);

    // ---- embedding fused with layer-0 ln1 DyT ----
    dyt_kernel<true><<<dim3(M_), 256, 0, stream>>>(
        nullptr, x, h, ln1_w, ln1_b, ln1_a, idx, wte, wpe);

    // ---- transformer layers ----
    for (int l = 0; l < L_; ++l) {
        if (l > 0)
            dyt_kernel<false><<<dim3(M_), 256, 0, stream>>>(
                x, nullptr, h, ln1_w + l * D_, ln1_b + l * D_, ln1_a + l,
                nullptr, nullptr, nullptr);
        gemm_btp<0><<<dim3(QKVN_ / 128, M_ / 128), 256, 0, stream>>>(
            h, wqkv_t + (size_t)l * QKVN_ * D_, nullptr, qkv, nullptr, nullptr, M_, QKVN_, D_);
        fattn_kernel<<<dim3(T_ / 64, H_, B_), 256, 0, stream>>>(qkv, attno);
        gemm_btp64<1><<<dim3(D_ / 128, M_ / 64), 256, 0, stream>>>(
            attno, wo_t + (size_t)l * D_ * D_, x, nullptr, bo + l * D_, x, M_, D_, D_);
        dyt_kernel<false><<<dim3(M_), 256, 0, stream>>>(
            x, nullptr, h, ln2_w + l * D_, ln2_b + l * D_, ln2_a + l,
            nullptr, nullptr, nullptr);
        gemm_btp<2><<<dim3(FF_ / 128, M_ / 128), 256, 0, stream>>>(
            h, wfc_t + (size_t)l * FF_ * D_, nullptr, mid, b_fc + l * FF_, nullptr, M_, FF_, D_);
        gemm_btp64<1><<<dim3(D_ / 128, M_ / 64), 256, 0, stream>>>(
            mid, wpr_t + (size_t)l * D_ * FF_, x, nullptr, b_pr + l * D_, x, M_, D_, FF_);
    }

    // ---- final DyT + lm_head (256x256 ring-4 pipelined) ----
    dyt_kernel<false><<<dim3(M_), 256, 0, stream>>>(
        x, nullptr, h, lnf_w, lnf_b, lnf_a, nullptr, nullptr, nullptr);
    gemm_lmhead<<<dim3((M_ / 256) * (V_ / 256)), 512, 0, stream>>>(h, wte_b, out);
}